// Round 1
// baseline (755.106 us; speedup 1.0000x reference)
//
#include <hip/hip_runtime.h>

#define M_TOT 32768  // B*N

typedef float f32x4 __attribute__((ext_vector_type(4)));
typedef short s16x8 __attribute__((ext_vector_type(8)));

#define AS1(p) ((__attribute__((address_space(1))) void*)(p))
#define AS3(p) ((__attribute__((address_space(3))) void*)(p))

__device__ __forceinline__ short f2bf(float f) {
    unsigned u = __builtin_bit_cast(unsigned, f);
    u += 0x7fffu + ((u >> 16) & 1u);
    return (short)(u >> 16);
}
__device__ __forceinline__ float bf2f(short s) {
    unsigned u = ((unsigned)(unsigned short)s) << 16;
    return __builtin_bit_cast(float, u);
}

// ---- convert query f32 -> bf16 ----
__global__ void conv_x(const float* __restrict__ x, short* __restrict__ y) {
    const size_t nchunk = (size_t)M_TOT * 1024 / 8;
    const size_t stride = (size_t)gridDim.x * blockDim.x;
    for (size_t c = (size_t)blockIdx.x * blockDim.x + threadIdx.x; c < nchunk; c += stride) {
        const float4* src = (const float4*)(x + c * 8);
        float4 a = src[0], b = src[1];
        s16x8 r;
        r[0] = f2bf(a.x); r[1] = f2bf(a.y); r[2] = f2bf(a.z); r[3] = f2bf(a.w);
        r[4] = f2bf(b.x); r[5] = f2bf(b.y); r[6] = f2bf(b.z); r[7] = f2bf(b.w);
        *(s16x8*)(y + c * 8) = r;
    }
}

// ---- weights: transpose+convert into Wcat[5120][1024] (rows = out-feature, cols = k) ----
__global__ void conv_w(const float* __restrict__ Wq, const float* __restrict__ Wk,
                       const float* __restrict__ Wv, const float* __restrict__ Wu,
                       const float* __restrict__ Wo, short* __restrict__ Wcat) {
    const int c = blockIdx.x * 256 + threadIdx.x;  // 5120*256 chunks of 4
    const int np = c >> 8;
    const int k0 = (c & 255) << 2;
    const float* W = (np < 1024) ? Wq : (np < 2048) ? Wk : (np < 3072) ? Wv
                   : (np < 4096) ? Wu : Wo;
    const int n = np & 1023;
    short4 r;
    r.x = f2bf(W[(size_t)(k0 + 0) * 1024 + n]);
    r.y = f2bf(W[(size_t)(k0 + 1) * 1024 + n]);
    r.z = f2bf(W[(size_t)(k0 + 2) * 1024 + n]);
    r.w = f2bf(W[(size_t)(k0 + 3) * 1024 + n]);
    *(short4*)(Wcat + (size_t)np * 1024 + k0) = r;
}

__global__ void conv_bias(const float* __restrict__ bq, const float* __restrict__ bk,
                          const float* __restrict__ bv, const float* __restrict__ bu,
                          const float* __restrict__ bo, float* __restrict__ bcat) {
    const int i = blockIdx.x * 256 + threadIdx.x;  // < 5120
    const float* b = (i < 1024) ? bq : (i < 2048) ? bk : (i < 3072) ? bv
                   : (i < 4096) ? bu : bo;
    bcat[i] = b[i & 1023];
}

// ---- main GEMM: C[M,1024*S] = A[M,1024] @ Wcat^T, 128x128 tile, BK=32 ----
// MODE 0: QKVU epilogue (q,u natural bf16; k,v transposed per head bf16)
// MODE 1: plain f32 out + bias
template <int MODE>
__global__ __launch_bounds__(256) void gemm_bf16(
        const short* __restrict__ A, const short* __restrict__ W,
        const float* __restrict__ bias,
        short* __restrict__ qb, short* __restrict__ ktb,
        short* __restrict__ vtb, short* __restrict__ ub,
        float* __restrict__ outb) {
    __shared__ short As[128 * 32];
    __shared__ short Bs[128 * 32];
    const int tid = threadIdx.x;
    const int wave = tid >> 6, lane = tid & 63;
    const int brow = blockIdx.y << 7;
    const int bcol = blockIdx.x << 7;
    const int wr = (wave >> 1) << 6, wc = (wave & 1) << 6;
    const int r16 = lane & 15;
    const int kq = (lane >> 4) << 3;
    const int cbase = (wave << 6) + lane;
    f32x4 acc[4][4] = {};
    for (int kt = 0; kt < 32; ++kt) {
        const int k0 = kt << 5;
        #pragma unroll
        for (int i = 0; i < 2; ++i) {
            const int c = (i << 8) + cbase;
            const short* ga = A + (size_t)(brow + (c >> 2)) * 1024 + k0 + ((c & 3) << 3);
            __builtin_amdgcn_global_load_lds(AS1(ga), AS3(&As[((i << 8) + (wave << 6)) * 8]), 16, 0, 0);
            const short* gb = W + (size_t)(bcol + (c >> 2)) * 1024 + k0 + ((c & 3) << 3);
            __builtin_amdgcn_global_load_lds(AS1(gb), AS3(&Bs[((i << 8) + (wave << 6)) * 8]), 16, 0, 0);
        }
        __syncthreads();
        s16x8 af[4], bf[4];
        #pragma unroll
        for (int m = 0; m < 4; ++m) af[m] = *(const s16x8*)(&As[(wr + m * 16 + r16) * 32 + kq]);
        #pragma unroll
        for (int n = 0; n < 4; ++n) bf[n] = *(const s16x8*)(&Bs[(wc + n * 16 + r16) * 32 + kq]);
        #pragma unroll
        for (int m = 0; m < 4; ++m)
            #pragma unroll
            for (int n = 0; n < 4; ++n)
                acc[m][n] = __builtin_amdgcn_mfma_f32_16x16x32_bf16(af[m], bf[n], acc[m][n], 0, 0, 0);
        __syncthreads();
    }
    const int rj = (lane >> 4) << 2;
    if (MODE == 1) {
        #pragma unroll
        for (int n = 0; n < 4; ++n) {
            const int gn = bcol + wc + n * 16 + r16;
            const float bv = bias[gn];
            #pragma unroll
            for (int m = 0; m < 4; ++m) {
                const int gm0 = brow + wr + m * 16 + rj;
                #pragma unroll
                for (int j = 0; j < 4; ++j)
                    outb[(size_t)(gm0 + j) * 1024 + gn] = acc[m][n][j] + bv;
            }
        }
    } else {
        const int seg = bcol >> 10;  // block-uniform
        if (seg == 0 || seg == 3) {
            short* dst = (seg == 0) ? qb : ub;
            const bool do_relu = (seg == 0);
            #pragma unroll
            for (int n = 0; n < 4; ++n) {
                const int gn = bcol + wc + n * 16 + r16;
                const int f = gn & 1023;
                const float bv = bias[gn];
                #pragma unroll
                for (int m = 0; m < 4; ++m) {
                    const int gm0 = brow + wr + m * 16 + rj;
                    #pragma unroll
                    for (int j = 0; j < 4; ++j) {
                        float val = acc[m][n][j] + bv;
                        if (do_relu) val = fmaxf(val, 0.0f);
                        dst[(size_t)(gm0 + j) * 1024 + f] = f2bf(val);
                    }
                }
            }
        } else {
            short* dst = (seg == 1) ? ktb : vtb;
            const bool do_relu = (seg == 1);
            #pragma unroll
            for (int n = 0; n < 4; ++n) {
                const int gn = bcol + wc + n * 16 + r16;
                const int hd = gn & 1023;  // h*64+d
                const float bv = bias[gn];
                #pragma unroll
                for (int m = 0; m < 4; ++m) {
                    const int gm0 = brow + wr + m * 16 + rj;  // token, multiple of 4
                    const int b = gm0 >> 13;
                    const int ntok = gm0 & 8191;
                    float v0 = acc[m][n][0] + bv, v1 = acc[m][n][1] + bv;
                    float v2 = acc[m][n][2] + bv, v3 = acc[m][n][3] + bv;
                    if (do_relu) {
                        v0 = fmaxf(v0, 0.0f); v1 = fmaxf(v1, 0.0f);
                        v2 = fmaxf(v2, 0.0f); v3 = fmaxf(v3, 0.0f);
                    }
                    short4 pk;
                    pk.x = f2bf(v0); pk.y = f2bf(v1); pk.z = f2bf(v2); pk.w = f2bf(v3);
                    *(short4*)(dst + ((size_t)(b * 1024 + hd)) * 8192 + ntok) = pk;
                }
            }
        }
    }
}

// ---- kv partials: one wave computes kv[64][64] over 256 tokens ----
__global__ __launch_bounds__(64) void kv_partial(const short* __restrict__ ktb,
                                                 const short* __restrict__ vtb,
                                                 float* __restrict__ kvp) {
    const int slice = blockIdx.x;  // 0..31
    const int bh = blockIdx.y;     // 0..63
    const int lane = threadIdx.x;
    const int r16 = lane & 15;
    const short* kb = ktb + (size_t)bh * 64 * 8192;
    const short* vb = vtb + (size_t)bh * 64 * 8192;
    const int n0 = slice << 8;
    f32x4 acc[4][4] = {};
    for (int s = 0; s < 8; ++s) {
        const int nk = n0 + (s << 5) + ((lane >> 4) << 3);
        s16x8 af[4], bf[4];
        #pragma unroll
        for (int m = 0; m < 4; ++m) af[m] = *(const s16x8*)(kb + (size_t)(m * 16 + r16) * 8192 + nk);
        #pragma unroll
        for (int n = 0; n < 4; ++n) bf[n] = *(const s16x8*)(vb + (size_t)(n * 16 + r16) * 8192 + nk);
        #pragma unroll
        for (int m = 0; m < 4; ++m)
            #pragma unroll
            for (int n = 0; n < 4; ++n)
                acc[m][n] = __builtin_amdgcn_mfma_f32_16x16x32_bf16(af[m], bf[n], acc[m][n], 0, 0, 0);
    }
    float* dst = kvp + ((size_t)slice * 64 + bh) * 4096;
    const int rj = (lane >> 4) << 2;
    #pragma unroll
    for (int m = 0; m < 4; ++m)
        #pragma unroll
        for (int n = 0; n < 4; ++n)
            #pragma unroll
            for (int j = 0; j < 4; ++j)
                dst[(size_t)(m * 16 + rj + j) * 64 + n * 16 + r16] = acc[m][n][j];
}

// ---- reduce 32 kv partials, abs-clamp, store transposed bf16 kv_t[bh][e][d] ----
__global__ void kv_reduce(const float* __restrict__ kvp, short* __restrict__ kvt) {
    const int bh = blockIdx.x;
    for (int i = threadIdx.x; i < 4096; i += 256) {
        float s = 0.0f;
        #pragma unroll 8
        for (int sl = 0; sl < 32; ++sl)
            s += kvp[((size_t)sl * 64 + bh) * 4096 + i];
        float a = fabsf(s);
        float cmag = fminf(fmaxf(a, 0.01f), 100.0f);
        float r = (s > 0.0f) ? cmag : ((s < 0.0f) ? -cmag : 0.0f);
        const int d = i >> 6, e = i & 63;
        kvt[(size_t)bh * 4096 + e * 64 + d] = f2bf(r);
    }
}

// ---- o = q @ kv  per (b,h), 256 tokens per block (4 waves x 64) ----
__global__ __launch_bounds__(256) void qkv_out(const short* __restrict__ qb,
                                               const short* __restrict__ kvt,
                                               float* __restrict__ ob) {
    const int bh = blockIdx.y;
    const int b = bh >> 4, h = bh & 15;
    const int tid = threadIdx.x;
    const int wave = tid >> 6, lane = tid & 63;
    const int r16 = lane & 15;
    const size_t mbase = (size_t)b * 8192 + ((size_t)blockIdx.x << 8) + (wave << 6);
    const short* kvb = kvt + (size_t)bh * 4096;
    f32x4 acc[4][4] = {};
    #pragma unroll
    for (int s = 0; s < 2; ++s) {
        const int kq2 = (s << 5) + ((lane >> 4) << 3);
        s16x8 af[4], bf[4];
        #pragma unroll
        for (int m = 0; m < 4; ++m)
            af[m] = *(const s16x8*)(qb + (mbase + m * 16 + r16) * 1024 + h * 64 + kq2);
        #pragma unroll
        for (int n = 0; n < 4; ++n)
            bf[n] = *(const s16x8*)(kvb + (n * 16 + r16) * 64 + kq2);
        #pragma unroll
        for (int m = 0; m < 4; ++m)
            #pragma unroll
            for (int n = 0; n < 4; ++n)
                acc[m][n] = __builtin_amdgcn_mfma_f32_16x16x32_bf16(af[m], bf[n], acc[m][n], 0, 0, 0);
    }
    const int rj = (lane >> 4) << 2;
    #pragma unroll
    for (int m = 0; m < 4; ++m)
        #pragma unroll
        for (int n = 0; n < 4; ++n)
            #pragma unroll
            for (int j = 0; j < 4; ++j)
                ob[(mbase + m * 16 + rj + j) * 1024 + h * 64 + n * 16 + r16] = acc[m][n][j];
}

// ---- LayerNorm over D=1024 + multiply by u, output bf16 ----
__global__ __launch_bounds__(256) void ln_mul(const float* __restrict__ ob,
                                              const short* __restrict__ ub,
                                              const float* __restrict__ lnw,
                                              const float* __restrict__ lnb,
                                              short* __restrict__ yb) {
    const int row = blockIdx.x;
    const int tid = threadIdx.x;
    const float4 v = ((const float4*)(ob + (size_t)row * 1024))[tid];
    float s = v.x + v.y + v.z + v.w;
    float sq = v.x * v.x + v.y * v.y + v.z * v.z + v.w * v.w;
    #pragma unroll
    for (int off = 32; off > 0; off >>= 1) {
        s += __shfl_down(s, off);
        sq += __shfl_down(sq, off);
    }
    __shared__ float ls[4], lq[4];
    const int wave = tid >> 6, lane = tid & 63;
    if (lane == 0) { ls[wave] = s; lq[wave] = sq; }
    __syncthreads();
    const float S = ls[0] + ls[1] + ls[2] + ls[3];
    const float SQ = lq[0] + lq[1] + lq[2] + lq[3];
    const float mu = S * (1.0f / 1024.0f);
    const float var = SQ * (1.0f / 1024.0f) - mu * mu;
    const float rs = rsqrtf(var + 1e-5f);
    const short4 uu = ((const short4*)(ub + (size_t)row * 1024))[tid];
    const float4 w = ((const float4*)lnw)[tid];
    const float4 bb = ((const float4*)lnb)[tid];
    short4 o;
    o.x = f2bf(bf2f(uu.x) * ((v.x - mu) * rs * w.x + bb.x));
    o.y = f2bf(bf2f(uu.y) * ((v.y - mu) * rs * w.y + bb.y));
    o.z = f2bf(bf2f(uu.z) * ((v.z - mu) * rs * w.z + bb.z));
    o.w = f2bf(bf2f(uu.w) * ((v.w - mu) * rs * w.w + bb.w));
    ((short4*)(yb + (size_t)row * 1024))[tid] = o;
}

extern "C" void kernel_launch(void* const* d_in, const int* in_sizes, int n_in,
                              void* d_out, int out_size, void* d_ws, size_t ws_size,
                              hipStream_t stream) {
    (void)in_sizes; (void)n_in; (void)out_size;
    const float* query = (const float*)d_in[0];
    const float* Wq = (const float*)d_in[1];
    const float* bq = (const float*)d_in[2];
    const float* Wk = (const float*)d_in[3];
    const float* bk = (const float*)d_in[4];
    const float* Wv = (const float*)d_in[5];
    const float* bv = (const float*)d_in[6];
    const float* Wu = (const float*)d_in[7];
    const float* bu = (const float*)d_in[8];
    const float* Wo = (const float*)d_in[9];
    const float* bo = (const float*)d_in[10];
    const float* lnw = (const float*)d_in[11];
    const float* lnb = (const float*)d_in[12];
    float* out = (float*)d_out;
    char* ws = (char*)d_ws;
    if (ws_size < 380129280u) return;  // needs ~362.5 MiB

    short* Xb   = (short*)(ws);                    // 64 MiB  (later aliased by yb)
    short* Wcat = (short*)(ws + 67108864);         // 10 MiB
    float* bcat = (float*)(ws + 77594624);         // 20 KiB
    short* qb   = (short*)(ws + 77615104);         // 64 MiB
    short* ktb  = (short*)(ws + 144723968);        // 64 MiB  (later aliased by ob)
    short* vtb  = (short*)(ws + 211832832);        // 64 MiB  (later aliased by ob)
    short* ub   = (short*)(ws + 278941696);        // 64 MiB
    float* kvp  = (float*)(ws + 346050560);        // 32 MiB
    short* kvt  = (short*)(ws + 379604992);        // 512 KiB
    float* ob   = (float*)(ws + 144723968);        // 128 MiB over dead ktb+vtb
    short* yb   = Xb;                              // 64 MiB over dead Xb

    conv_x<<<2048, 256, 0, stream>>>(query, Xb);
    conv_w<<<5120, 256, 0, stream>>>(Wq, Wk, Wv, Wu, Wo, Wcat);
    conv_bias<<<20, 256, 0, stream>>>(bq, bk, bv, bu, bo, bcat);
    gemm_bf16<0><<<dim3(32, 256), 256, 0, stream>>>(Xb, Wcat, bcat, qb, ktb, vtb, ub, nullptr);
    kv_partial<<<dim3(32, 64), 64, 0, stream>>>(ktb, vtb, kvp);
    kv_reduce<<<64, 256, 0, stream>>>(kvp, kvt);
    qkv_out<<<dim3(32, 64), 256, 0, stream>>>(qb, kvt, ob);
    ln_mul<<<32768, 256, 0, stream>>>(ob, ub, lnw, lnb, yb);
    gemm_bf16<1><<<dim3(8, 256), 256, 0, stream>>>(yb, Wcat + (size_t)4096 * 1024, bcat + 4096,
                                                   nullptr, nullptr, nullptr, nullptr, out);
}

// Round 2
// 657.514 us; speedup vs baseline: 1.1484x; 1.1484x over previous
//
#include <hip/hip_runtime.h>

#define M_TOT 32768  // B*N

typedef float f32x4 __attribute__((ext_vector_type(4)));
typedef short s16x8 __attribute__((ext_vector_type(8)));

#define AS1(p) ((__attribute__((address_space(1))) void*)(p))
#define AS3(p) ((__attribute__((address_space(3))) void*)(p))

#define BARRIER() asm volatile("s_barrier" ::: "memory")
#define VMCNT8() asm volatile("s_waitcnt vmcnt(8)" ::: "memory")
#define VMCNT4() asm volatile("s_waitcnt vmcnt(4)" ::: "memory")
#define VMCNT0() asm volatile("s_waitcnt vmcnt(0)" ::: "memory")

__device__ __forceinline__ short f2bf(float f) {
    unsigned u = __builtin_bit_cast(unsigned, f);
    u += 0x7fffu + ((u >> 16) & 1u);
    return (short)(u >> 16);
}
__device__ __forceinline__ float bf2f(short s) {
    unsigned u = ((unsigned)(unsigned short)s) << 16;
    return __builtin_bit_cast(float, u);
}

// ---- convert query f32 -> bf16 ----
__global__ void conv_x(const float* __restrict__ x, short* __restrict__ y) {
    const size_t nchunk = (size_t)M_TOT * 1024 / 8;
    const size_t stride = (size_t)gridDim.x * blockDim.x;
    for (size_t c = (size_t)blockIdx.x * blockDim.x + threadIdx.x; c < nchunk; c += stride) {
        const float4* src = (const float4*)(x + c * 8);
        float4 a = src[0], b = src[1];
        s16x8 r;
        r[0] = f2bf(a.x); r[1] = f2bf(a.y); r[2] = f2bf(a.z); r[3] = f2bf(a.w);
        r[4] = f2bf(b.x); r[5] = f2bf(b.y); r[6] = f2bf(b.z); r[7] = f2bf(b.w);
        *(s16x8*)(y + c * 8) = r;
    }
}

// ---- weights: transpose+convert into Wcat[5120][1024] (rows = out-feature, cols = k) ----
__global__ void conv_w(const float* __restrict__ Wq, const float* __restrict__ Wk,
                       const float* __restrict__ Wv, const float* __restrict__ Wu,
                       const float* __restrict__ Wo, short* __restrict__ Wcat) {
    const int c = blockIdx.x * 256 + threadIdx.x;  // 5120*256 chunks of 4
    const int np = c >> 8;
    const int k0 = (c & 255) << 2;
    const float* W = (np < 1024) ? Wq : (np < 2048) ? Wk : (np < 3072) ? Wv
                   : (np < 4096) ? Wu : Wo;
    const int n = np & 1023;
    short4 r;
    r.x = f2bf(W[(size_t)(k0 + 0) * 1024 + n]);
    r.y = f2bf(W[(size_t)(k0 + 1) * 1024 + n]);
    r.z = f2bf(W[(size_t)(k0 + 2) * 1024 + n]);
    r.w = f2bf(W[(size_t)(k0 + 3) * 1024 + n]);
    *(short4*)(Wcat + (size_t)np * 1024 + k0) = r;
}

__global__ void conv_bias(const float* __restrict__ bq, const float* __restrict__ bk,
                          const float* __restrict__ bv, const float* __restrict__ bu,
                          const float* __restrict__ bo, float* __restrict__ bcat) {
    const int i = blockIdx.x * 256 + threadIdx.x;  // < 5120
    const float* b = (i < 1024) ? bq : (i < 2048) ? bk : (i < 3072) ? bv
                   : (i < 4096) ? bu : bo;
    bcat[i] = b[i & 1023];
}

// ---- deep-pipelined 256x256 GEMM, BK=32, 4 LDS buffers (race-free), counted vmcnt ----
// A[M][1024] bf16, W rows = out-feature (B^T). 8 waves, per-wave C = 128x64.
// LDS swizzle: byte ^= ((byte>>7)&3)<<4 within each 16KB [256][32]bf16 tile
// (involution; applied on the global SOURCE address for global_load_lds and on
// the ds_read address -> both-sides-consistent, rule #21).
template <int MODE>
__global__ __launch_bounds__(512, 2) void gemm8(
        const short* __restrict__ A, const short* __restrict__ W,
        const float* __restrict__ bias,
        short* __restrict__ qb, short* __restrict__ ktb,
        short* __restrict__ vtb, short* __restrict__ ub,
        float* __restrict__ outb) {
    extern __shared__ char lds[];
    const int tid = threadIdx.x;
    const int wave = tid >> 6, lane = tid & 63;
    const int r16 = lane & 15;
    // swizzled k-chunk byte offset for fragment reads (lane-constant)
    const int g2 = (((lane >> 4) ^ ((r16 >> 1) & 3)) << 4);
    // staging source coords (lane-constant): row within half-tile, permuted 16B chunk
    const int srow = wave * 16 + (lane >> 2);
    const int scol = (((lane & 3) ^ ((lane >> 3) & 3)) << 4);
    const int moff = (wave >> 2) << 7;  // 0 / 128
    const int noff = (wave & 3) << 6;   // 0 / 64 / 128 / 192

    const int nwg = (MODE == 0) ? 2048 : 512;
    const int bid = blockIdx.x;
    const int swz = (bid & 7) * (nwg >> 3) + (bid >> 3);  // XCD-chunked (nwg%8==0)
    const int mblk = swz & 127, nblk = swz >> 7;          // M-major within chunk
    const int row0 = mblk << 8, col0 = nblk << 8;

    const char* Agl = (const char*)A;
    const char* Wgl = (const char*)W;

#define STAGE(GB, R0, T, DST)                                                  \
    { _Pragma("unroll") for (int ld_ = 0; ld_ < 2; ++ld_) {                    \
        const char* g_ = (GB) + (size_t)((R0) + ld_ * 128 + srow) * 2048 +     \
                         (size_t)(T) * 64 + scol;                              \
        __builtin_amdgcn_global_load_lds(AS1(g_),                              \
            AS3((DST) + ld_ * 8192 + wave * 1024), 16, 0, 0); } }

#define RD(REG, RB) (*(const s16x8*)((REG) + ((RB) + r16) * 64 + g2))

    f32x4 acc[8][4] = {};
    s16x8 bfr[4];

    // prologue: stage tiles 0..2 (12 loads/thread), wait tile 0 (8 in flight)
    #pragma unroll
    for (int t = 0; t < 3; ++t) {
        char* dst = lds + (t & 3) * 32768;
        STAGE(Agl, row0, t, dst);
        STAGE(Wgl, col0, t, dst + 16384);
    }
    VMCNT8();
    BARRIER();

#define TILE(T, DOSTAGE, TRAIL)                                                \
    { char* Ar_ = lds + ((T) & 3) * 32768; char* Br_ = Ar_ + 16384;            \
      char* Sr_ = lds + (((T) + 3) & 3) * 32768;                               \
      s16x8 afr[4];                                                            \
      _Pragma("unroll") for (int n = 0; n < 4; ++n) bfr[n] = RD(Br_, noff + n * 16); \
      _Pragma("unroll") for (int m = 0; m < 4; ++m) afr[m] = RD(Ar_, moff + m * 16); \
      if (DOSTAGE) STAGE(Agl, row0, (T) + 3, Sr_);                             \
      BARRIER();                                                               \
      __builtin_amdgcn_s_setprio(1);                                           \
      _Pragma("unroll") for (int m = 0; m < 4; ++m)                            \
        _Pragma("unroll") for (int n = 0; n < 4; ++n)                          \
          acc[m][n] = __builtin_amdgcn_mfma_f32_16x16x32_bf16(afr[m], bfr[n], acc[m][n], 0, 0, 0); \
      __builtin_amdgcn_s_setprio(0);                                           \
      BARRIER();                                                               \
      _Pragma("unroll") for (int m = 0; m < 4; ++m) afr[m] = RD(Ar_, moff + 64 + m * 16); \
      if (DOSTAGE) STAGE(Wgl, col0, (T) + 3, Sr_ + 16384);                     \
      BARRIER();                                                               \
      __builtin_amdgcn_s_setprio(1);                                           \
      _Pragma("unroll") for (int m = 0; m < 4; ++m)                            \
        _Pragma("unroll") for (int n = 0; n < 4; ++n)                          \
          acc[m + 4][n] = __builtin_amdgcn_mfma_f32_16x16x32_bf16(afr[m], bfr[n], acc[m + 4][n], 0, 0, 0); \
      __builtin_amdgcn_s_setprio(0);                                           \
      TRAIL;                                                                   \
      BARRIER(); }

    #pragma unroll 1
    for (int t = 0; t < 29; ++t) TILE(t, true, VMCNT8());
    TILE(29, false, VMCNT4());
    TILE(30, false, VMCNT0());
    TILE(31, false, (void)0);

    // ---- epilogue ----
    const int rj = (lane >> 4) << 2;
    if (MODE == 1) {
        #pragma unroll
        for (int n = 0; n < 4; ++n) {
            const int gn = col0 + noff + n * 16 + r16;
            const float bv = bias[gn];
            #pragma unroll
            for (int m = 0; m < 8; ++m) {
                const int gm0 = row0 + moff + m * 16 + rj;
                #pragma unroll
                for (int j = 0; j < 4; ++j)
                    outb[(size_t)(gm0 + j) * 1024 + gn] = acc[m][n][j] + bv;
            }
        }
    } else {
        const int seg = col0 >> 10;  // block-uniform (256-col block within one 1024 seg)
        if (seg == 0 || seg == 3) {
            short* dst = (seg == 0) ? qb : ub;
            const bool do_relu = (seg == 0);
            #pragma unroll
            for (int n = 0; n < 4; ++n) {
                const int gn = col0 + noff + n * 16 + r16;
                const int f = gn & 1023;
                const float bv = bias[gn];
                #pragma unroll
                for (int m = 0; m < 8; ++m) {
                    const int gm0 = row0 + moff + m * 16 + rj;
                    #pragma unroll
                    for (int j = 0; j < 4; ++j) {
                        float val = acc[m][n][j] + bv;
                        if (do_relu) val = fmaxf(val, 0.0f);
                        dst[(size_t)(gm0 + j) * 1024 + f] = f2bf(val);
                    }
                }
            }
        } else {
            short* dst = (seg == 1) ? ktb : vtb;
            const bool do_relu = (seg == 1);
            #pragma unroll
            for (int n = 0; n < 4; ++n) {
                const int gn = col0 + noff + n * 16 + r16;
                const int hd = gn & 1023;  // h*64+d
                const float bv = bias[gn];
                #pragma unroll
                for (int m = 0; m < 8; ++m) {
                    const int gm0 = row0 + moff + m * 16 + rj;  // token, multiple of 4
                    const int b = gm0 >> 13;
                    const int ntok = gm0 & 8191;
                    float v0 = acc[m][n][0] + bv, v1 = acc[m][n][1] + bv;
                    float v2 = acc[m][n][2] + bv, v3 = acc[m][n][3] + bv;
                    if (do_relu) {
                        v0 = fmaxf(v0, 0.0f); v1 = fmaxf(v1, 0.0f);
                        v2 = fmaxf(v2, 0.0f); v3 = fmaxf(v3, 0.0f);
                    }
                    short4 pk;
                    pk.x = f2bf(v0); pk.y = f2bf(v1); pk.z = f2bf(v2); pk.w = f2bf(v3);
                    *(short4*)(dst + ((size_t)(b * 1024 + hd)) * 8192 + ntok) = pk;
                }
            }
        }
    }
#undef TILE
#undef RD
#undef STAGE
}

// ---- kv partials: one wave computes kv[64][64] over 256 tokens ----
__global__ __launch_bounds__(64) void kv_partial(const short* __restrict__ ktb,
                                                 const short* __restrict__ vtb,
                                                 float* __restrict__ kvp) {
    const int slice = blockIdx.x;  // 0..31
    const int bh = blockIdx.y;     // 0..63
    const int lane = threadIdx.x;
    const int r16 = lane & 15;
    const short* kb = ktb + (size_t)bh * 64 * 8192;
    const short* vb = vtb + (size_t)bh * 64 * 8192;
    const int n0 = slice << 8;
    f32x4 acc[4][4] = {};
    for (int s = 0; s < 8; ++s) {
        const int nk = n0 + (s << 5) + ((lane >> 4) << 3);
        s16x8 af[4], bf[4];
        #pragma unroll
        for (int m = 0; m < 4; ++m) af[m] = *(const s16x8*)(kb + (size_t)(m * 16 + r16) * 8192 + nk);
        #pragma unroll
        for (int n = 0; n < 4; ++n) bf[n] = *(const s16x8*)(vb + (size_t)(n * 16 + r16) * 8192 + nk);
        #pragma unroll
        for (int m = 0; m < 4; ++m)
            #pragma unroll
            for (int n = 0; n < 4; ++n)
                acc[m][n] = __builtin_amdgcn_mfma_f32_16x16x32_bf16(af[m], bf[n], acc[m][n], 0, 0, 0);
    }
    float* dst = kvp + ((size_t)slice * 64 + bh) * 4096;
    const int rj = (lane >> 4) << 2;
    #pragma unroll
    for (int m = 0; m < 4; ++m)
        #pragma unroll
        for (int n = 0; n < 4; ++n)
            #pragma unroll
            for (int j = 0; j < 4; ++j)
                dst[(size_t)(m * 16 + rj + j) * 64 + n * 16 + r16] = acc[m][n][j];
}

// ---- reduce 32 kv partials, abs-clamp, store transposed bf16 kv_t[bh][e][d] ----
__global__ void kv_reduce(const float* __restrict__ kvp, short* __restrict__ kvt) {
    const int bh = blockIdx.x;
    for (int i = threadIdx.x; i < 4096; i += 256) {
        float s = 0.0f;
        #pragma unroll 8
        for (int sl = 0; sl < 32; ++sl)
            s += kvp[((size_t)sl * 64 + bh) * 4096 + i];
        float a = fabsf(s);
        float cmag = fminf(fmaxf(a, 0.01f), 100.0f);
        float r = (s > 0.0f) ? cmag : ((s < 0.0f) ? -cmag : 0.0f);
        const int d = i >> 6, e = i & 63;
        kvt[(size_t)bh * 4096 + e * 64 + d] = f2bf(r);
    }
}

// ---- o = q @ kv  per (b,h), 256 tokens per block (4 waves x 64) ----
__global__ __launch_bounds__(256) void qkv_out(const short* __restrict__ qb,
                                               const short* __restrict__ kvt,
                                               float* __restrict__ ob) {
    const int bh = blockIdx.y;
    const int b = bh >> 4, h = bh & 15;
    const int tid = threadIdx.x;
    const int wave = tid >> 6, lane = tid & 63;
    const int r16 = lane & 15;
    const size_t mbase = (size_t)b * 8192 + ((size_t)blockIdx.x << 8) + (wave << 6);
    const short* kvb = kvt + (size_t)bh * 4096;
    f32x4 acc[4][4] = {};
    #pragma unroll
    for (int s = 0; s < 2; ++s) {
        const int kq2 = (s << 5) + ((lane >> 4) << 3);
        s16x8 af[4], bf[4];
        #pragma unroll
        for (int m = 0; m < 4; ++m)
            af[m] = *(const s16x8*)(qb + (mbase + m * 16 + r16) * 1024 + h * 64 + kq2);
        #pragma unroll
        for (int n = 0; n < 4; ++n)
            bf[n] = *(const s16x8*)(kvb + (n * 16 + r16) * 64 + kq2);
        #pragma unroll
        for (int m = 0; m < 4; ++m)
            #pragma unroll
            for (int n = 0; n < 4; ++n)
                acc[m][n] = __builtin_amdgcn_mfma_f32_16x16x32_bf16(af[m], bf[n], acc[m][n], 0, 0, 0);
    }
    const int rj = (lane >> 4) << 2;
    #pragma unroll
    for (int m = 0; m < 4; ++m)
        #pragma unroll
        for (int n = 0; n < 4; ++n)
            #pragma unroll
            for (int j = 0; j < 4; ++j)
                ob[(mbase + m * 16 + rj + j) * 1024 + h * 64 + n * 16 + r16] = acc[m][n][j];
}

// ---- LayerNorm over D=1024 + multiply by u, output bf16 ----
__global__ __launch_bounds__(256) void ln_mul(const float* __restrict__ ob,
                                              const short* __restrict__ ub,
                                              const float* __restrict__ lnw,
                                              const float* __restrict__ lnb,
                                              short* __restrict__ yb) {
    const int row = blockIdx.x;
    const int tid = threadIdx.x;
    const float4 v = ((const float4*)(ob + (size_t)row * 1024))[tid];
    float s = v.x + v.y + v.z + v.w;
    float sq = v.x * v.x + v.y * v.y + v.z * v.z + v.w * v.w;
    #pragma unroll
    for (int off = 32; off > 0; off >>= 1) {
        s += __shfl_down(s, off);
        sq += __shfl_down(sq, off);
    }
    __shared__ float ls[4], lq[4];
    const int wave = tid >> 6, lane = tid & 63;
    if (lane == 0) { ls[wave] = s; lq[wave] = sq; }
    __syncthreads();
    const float S = ls[0] + ls[1] + ls[2] + ls[3];
    const float SQ = lq[0] + lq[1] + lq[2] + lq[3];
    const float mu = S * (1.0f / 1024.0f);
    const float var = SQ * (1.0f / 1024.0f) - mu * mu;
    const float rs = rsqrtf(var + 1e-5f);
    const short4 uu = ((const short4*)(ub + (size_t)row * 1024))[tid];
    const float4 w = ((const float4*)lnw)[tid];
    const float4 bb = ((const float4*)lnb)[tid];
    short4 o;
    o.x = f2bf(bf2f(uu.x) * ((v.x - mu) * rs * w.x + bb.x));
    o.y = f2bf(bf2f(uu.y) * ((v.y - mu) * rs * w.y + bb.y));
    o.z = f2bf(bf2f(uu.z) * ((v.z - mu) * rs * w.z + bb.z));
    o.w = f2bf(bf2f(uu.w) * ((v.w - mu) * rs * w.w + bb.w));
    ((short4*)(yb + (size_t)row * 1024))[tid] = o;
}

extern "C" void kernel_launch(void* const* d_in, const int* in_sizes, int n_in,
                              void* d_out, int out_size, void* d_ws, size_t ws_size,
                              hipStream_t stream) {
    (void)in_sizes; (void)n_in; (void)out_size;
    const float* query = (const float*)d_in[0];
    const float* Wq = (const float*)d_in[1];
    const float* bq = (const float*)d_in[2];
    const float* Wk = (const float*)d_in[3];
    const float* bk = (const float*)d_in[4];
    const float* Wv = (const float*)d_in[5];
    const float* bv = (const float*)d_in[6];
    const float* Wu = (const float*)d_in[7];
    const float* bu = (const float*)d_in[8];
    const float* Wo = (const float*)d_in[9];
    const float* bo = (const float*)d_in[10];
    const float* lnw = (const float*)d_in[11];
    const float* lnb = (const float*)d_in[12];
    float* out = (float*)d_out;
    char* ws = (char*)d_ws;
    if (ws_size < 380129280u) return;  // needs ~362.5 MiB

    short* Xb   = (short*)(ws);                    // 64 MiB  (later aliased by yb)
    short* Wcat = (short*)(ws + 67108864);         // 10 MiB
    float* bcat = (float*)(ws + 77594624);         // 20 KiB
    short* qb   = (short*)(ws + 77615104);         // 64 MiB
    short* ktb  = (short*)(ws + 144723968);        // 64 MiB  (later aliased by ob)
    short* vtb  = (short*)(ws + 211832832);        // 64 MiB  (later aliased by ob)
    short* ub   = (short*)(ws + 278941696);        // 64 MiB
    float* kvp  = (float*)(ws + 346050560);        // 32 MiB
    short* kvt  = (short*)(ws + 379604992);        // 512 KiB
    float* ob   = (float*)(ws + 144723968);        // 128 MiB over dead ktb+vtb
    short* yb   = Xb;                              // 64 MiB over dead Xb

    hipFuncSetAttribute(reinterpret_cast<const void*>(&gemm8<0>),
                        hipFuncAttributeMaxDynamicSharedMemorySize, 131072);
    hipFuncSetAttribute(reinterpret_cast<const void*>(&gemm8<1>),
                        hipFuncAttributeMaxDynamicSharedMemorySize, 131072);

    conv_x<<<2048, 256, 0, stream>>>(query, Xb);
    conv_w<<<5120, 256, 0, stream>>>(Wq, Wk, Wv, Wu, Wo, Wcat);
    conv_bias<<<20, 256, 0, stream>>>(bq, bk, bv, bu, bo, bcat);
    gemm8<0><<<2048, 512, 131072, stream>>>(Xb, Wcat, bcat, qb, ktb, vtb, ub, nullptr);
    kv_partial<<<dim3(32, 64), 64, 0, stream>>>(ktb, vtb, kvp);
    kv_reduce<<<64, 256, 0, stream>>>(kvp, kvt);
    qkv_out<<<dim3(32, 64), 256, 0, stream>>>(qb, kvt, ob);
    ln_mul<<<32768, 256, 0, stream>>>(ob, ub, lnw, lnb, yb);
    gemm8<1><<<512, 512, 131072, stream>>>(yb, Wcat + (size_t)4096 * 1024, bcat + 4096,
                                           nullptr, nullptr, nullptr, nullptr, out);
}

// Round 3
// 600.541 us; speedup vs baseline: 1.2574x; 1.0949x over previous
//
#include <hip/hip_runtime.h>

#define M_TOT 32768  // B*N

typedef float f32x4 __attribute__((ext_vector_type(4)));
typedef short s16x8 __attribute__((ext_vector_type(8)));

#define AS1(p) ((__attribute__((address_space(1))) void*)(p))
#define AS3(p) ((__attribute__((address_space(3))) void*)(p))

#define BARRIER() asm volatile("s_barrier" ::: "memory")
#define VMCNT4() asm volatile("s_waitcnt vmcnt(4)" ::: "memory")
#define VMCNT2() asm volatile("s_waitcnt vmcnt(2)" ::: "memory")
#define VMCNT0() asm volatile("s_waitcnt vmcnt(0)" ::: "memory")

__device__ __forceinline__ short f2bf(float f) {
    unsigned u = __builtin_bit_cast(unsigned, f);
    u += 0x7fffu + ((u >> 16) & 1u);
    return (short)(u >> 16);
}
__device__ __forceinline__ float bf2f(short s) {
    unsigned u = ((unsigned)(unsigned short)s) << 16;
    return __builtin_bit_cast(float, u);
}

// ---- convert query f32 -> bf16 ----
__global__ void conv_x(const float* __restrict__ x, short* __restrict__ y) {
    const size_t nchunk = (size_t)M_TOT * 1024 / 8;
    const size_t stride = (size_t)gridDim.x * blockDim.x;
    for (size_t c = (size_t)blockIdx.x * blockDim.x + threadIdx.x; c < nchunk; c += stride) {
        const float4* src = (const float4*)(x + c * 8);
        float4 a = src[0], b = src[1];
        s16x8 r;
        r[0] = f2bf(a.x); r[1] = f2bf(a.y); r[2] = f2bf(a.z); r[3] = f2bf(a.w);
        r[4] = f2bf(b.x); r[5] = f2bf(b.y); r[6] = f2bf(b.z); r[7] = f2bf(b.w);
        *(s16x8*)(y + c * 8) = r;
    }
}

// ---- weights: transpose+convert into Wcat[5120][1024] (rows = out-feature, cols = k) ----
__global__ void conv_w(const float* __restrict__ Wq, const float* __restrict__ Wk,
                       const float* __restrict__ Wv, const float* __restrict__ Wu,
                       const float* __restrict__ Wo, short* __restrict__ Wcat) {
    const int c = blockIdx.x * 256 + threadIdx.x;  // 5120*256 chunks of 4
    const int np = c >> 8;
    const int k0 = (c & 255) << 2;
    const float* W = (np < 1024) ? Wq : (np < 2048) ? Wk : (np < 3072) ? Wv
                   : (np < 4096) ? Wu : Wo;
    const int n = np & 1023;
    short4 r;
    r.x = f2bf(W[(size_t)(k0 + 0) * 1024 + n]);
    r.y = f2bf(W[(size_t)(k0 + 1) * 1024 + n]);
    r.z = f2bf(W[(size_t)(k0 + 2) * 1024 + n]);
    r.w = f2bf(W[(size_t)(k0 + 3) * 1024 + n]);
    *(short4*)(Wcat + (size_t)np * 1024 + k0) = r;
}

__global__ void conv_bias(const float* __restrict__ bq, const float* __restrict__ bk,
                          const float* __restrict__ bv, const float* __restrict__ bu,
                          const float* __restrict__ bo, float* __restrict__ bcat) {
    const int i = blockIdx.x * 256 + threadIdx.x;  // < 5120
    const float* b = (i < 1024) ? bq : (i < 2048) ? bk : (i < 3072) ? bv
                   : (i < 4096) ? bu : bo;
    bcat[i] = b[i & 1023];
}

// ---- 256x256 GEMM, BK=64, 2 LDS buffers, 4 fine phases/K-tile, counted vmcnt ----
// Stage order per tile t (into other buffer, for t+1): (B0,B1)(B2,B3)(A0,A2)(A1,A3).
// Waits: vmcnt(4) end-ph2 (forces A1,A3 of t), vmcnt(2) end-ph4 (forces B*+A0,A2 of t+1).
// LDS rows are 128B (64 bf16); swizzle: 16B-chunk ^= (row&7), pre-swizzled on the
// global source for global_load_lds and applied on ds_read (involution, both sides).
template <int MODE>
__global__ __launch_bounds__(512, 2) void gemm8(
        const short* __restrict__ A, const short* __restrict__ W,
        const float* __restrict__ bias,
        short* __restrict__ qb, short* __restrict__ ktb,
        short* __restrict__ vtb, short* __restrict__ ub,
        float* __restrict__ outb) {
    extern __shared__ char lds[];
    const int tid = threadIdx.x;
    const int wave = tid >> 6, lane = tid & 63;
    const int r16 = lane & 15, g = lane >> 4;
    const int moff = (wave >> 2) << 7;  // 0 / 128
    const int noff = (wave & 3) << 6;   // 0 / 64 / 128 / 192

    const int nwg = (MODE == 0) ? 2048 : 512;
    const int NB = (MODE == 0) ? 16 : 4;
    const int bid = blockIdx.x;
    const int swz = (bid & 7) * (nwg >> 3) + (bid >> 3);  // XCD-chunked (nwg%8==0)
    const int mblk = swz / NB, nblk = swz % NB;           // M-outer: XCDs own disjoint A-slices
    const int row0 = mblk << 8, col0 = nblk << 8;

    // ds_read swizzled chunk offsets (lane-constant)
    const int rswz = r16 & 7;
    const int ck0 = (g ^ rswz) << 4;
    const int ck1 = ((4 + g) ^ rswz) << 4;
    const int rowbA = (moff + r16) << 7;
    const int rowbB = (noff + r16) << 7;

    // staging source (lane-constant): row-in-inst = wave*8 + (lane>>3), chunk pre-swizzled
    const char* baseA = (const char*)A + (size_t)(row0 + wave * 8 + (lane >> 3)) * 2048
                        + (((lane & 7) ^ ((lane >> 3) & 7)) << 4);
    const char* baseB = (const char*)W + (size_t)(col0 + wave * 8 + (lane >> 3)) * 2048
                        + (((lane & 7) ^ ((lane >> 3) & 7)) << 4);

#define STG(BASE, J, T, DST)                                                   \
    __builtin_amdgcn_global_load_lds(                                          \
        AS1((BASE) + (size_t)(J) * 131072 + (size_t)(T) * 128),                \
        AS3((DST) + (J) * 8192 + wave * 1024), 16, 0, 0)

#define RDA(V, M, BUFA) {                                                      \
    (V)[0] = *(const s16x8*)((BUFA) + rowbA + (M) * 2048 + ck0);               \
    (V)[1] = *(const s16x8*)((BUFA) + rowbA + (M) * 2048 + ck1); }

#define RDB(V, N, BUFB) {                                                      \
    (V)[0] = *(const s16x8*)((BUFB) + rowbB + (N) * 2048 + ck0);               \
    (V)[1] = *(const s16x8*)((BUFB) + rowbB + (N) * 2048 + ck1); }

#define MF16(P)                                                                \
    _Pragma("unroll") for (int n = 0; n < 4; ++n) {                            \
        acc[2*(P)][n]   = __builtin_amdgcn_mfma_f32_16x16x32_bf16(afr[0][0], bfr[n][0], acc[2*(P)][n], 0, 0, 0);   \
        acc[2*(P)+1][n] = __builtin_amdgcn_mfma_f32_16x16x32_bf16(afr[1][0], bfr[n][0], acc[2*(P)+1][n], 0, 0, 0); \
        acc[2*(P)][n]   = __builtin_amdgcn_mfma_f32_16x16x32_bf16(afr[0][1], bfr[n][1], acc[2*(P)][n], 0, 0, 0);   \
        acc[2*(P)+1][n] = __builtin_amdgcn_mfma_f32_16x16x32_bf16(afr[1][1], bfr[n][1], acc[2*(P)+1][n], 0, 0, 0); \
    }

#define TILE(T, DOSTAGE, TR2, TR4) {                                           \
    char* bA_ = lds + ((T) & 1) * 65536; char* bB_ = bA_ + 32768;              \
    char* sA_ = lds + (((T) + 1) & 1) * 65536; char* sB_ = sA_ + 32768;        \
    s16x8 afr[2][2];                                                           \
    if (DOSTAGE) { STG(baseB, 0, (T) + 1, sB_); STG(baseB, 1, (T) + 1, sB_); } \
    _Pragma("unroll") for (int n = 0; n < 4; ++n) RDB(bfr[n], n, bB_);         \
    RDA(afr[0], 0, bA_); RDA(afr[1], 1, bA_);                                  \
    BARRIER(); __builtin_amdgcn_s_setprio(1); MF16(0);                         \
    __builtin_amdgcn_s_setprio(0); BARRIER();                                  \
    if (DOSTAGE) { STG(baseB, 2, (T) + 1, sB_); STG(baseB, 3, (T) + 1, sB_); } \
    RDA(afr[0], 2, bA_); RDA(afr[1], 3, bA_);                                  \
    BARRIER(); __builtin_amdgcn_s_setprio(1); MF16(1);                         \
    __builtin_amdgcn_s_setprio(0); TR2; BARRIER();                             \
    if (DOSTAGE) { STG(baseA, 0, (T) + 1, sA_); STG(baseA, 2, (T) + 1, sA_); } \
    RDA(afr[0], 4, bA_); RDA(afr[1], 5, bA_);                                  \
    BARRIER(); __builtin_amdgcn_s_setprio(1); MF16(2);                         \
    __builtin_amdgcn_s_setprio(0); BARRIER();                                  \
    if (DOSTAGE) { STG(baseA, 1, (T) + 1, sA_); STG(baseA, 3, (T) + 1, sA_); } \
    RDA(afr[0], 6, bA_); RDA(afr[1], 7, bA_);                                  \
    BARRIER(); __builtin_amdgcn_s_setprio(1); MF16(3);                         \
    __builtin_amdgcn_s_setprio(0); TR4; BARRIER();                             \
}

    f32x4 acc[8][4] = {};
    s16x8 bfr[4][2];

    // prologue: stage tile 0 in steady-state issue order, keep A1,A3 in flight
    STG(baseB, 0, 0, lds + 32768); STG(baseB, 1, 0, lds + 32768);
    STG(baseB, 2, 0, lds + 32768); STG(baseB, 3, 0, lds + 32768);
    STG(baseA, 0, 0, lds);         STG(baseA, 2, 0, lds);
    STG(baseA, 1, 0, lds);         STG(baseA, 3, 0, lds);
    VMCNT2();
    BARRIER();

    #pragma unroll 1
    for (int t = 0; t < 15; ++t) TILE(t, true, VMCNT4(), VMCNT2());
    TILE(15, false, VMCNT0(), (void)0);

    // ---- epilogue ----
    const int rj = (lane >> 4) << 2;
    if (MODE == 1) {
        #pragma unroll
        for (int n = 0; n < 4; ++n) {
            const int gn = col0 + noff + n * 16 + r16;
            const float bv = bias[gn];
            #pragma unroll
            for (int m = 0; m < 8; ++m) {
                const int gm0 = row0 + moff + m * 16 + rj;
                #pragma unroll
                for (int j = 0; j < 4; ++j)
                    outb[(size_t)(gm0 + j) * 1024 + gn] = acc[m][n][j] + bv;
            }
        }
    } else {
        const int seg = col0 >> 10;  // block-uniform (256-col block within one 1024 seg)
        if (seg == 0 || seg == 3) {
            short* dst = (seg == 0) ? qb : ub;
            const bool do_relu = (seg == 0);
            #pragma unroll
            for (int n = 0; n < 4; ++n) {
                const int gn = col0 + noff + n * 16 + r16;
                const int f = gn & 1023;
                const float bv = bias[gn];
                #pragma unroll
                for (int m = 0; m < 8; ++m) {
                    const int gm0 = row0 + moff + m * 16 + rj;
                    #pragma unroll
                    for (int j = 0; j < 4; ++j) {
                        float val = acc[m][n][j] + bv;
                        if (do_relu) val = fmaxf(val, 0.0f);
                        dst[(size_t)(gm0 + j) * 1024 + f] = f2bf(val);
                    }
                }
            }
        } else {
            short* dst = (seg == 1) ? ktb : vtb;
            const bool do_relu = (seg == 1);
            #pragma unroll
            for (int n = 0; n < 4; ++n) {
                const int gn = col0 + noff + n * 16 + r16;
                const int hd = gn & 1023;  // h*64+d
                const float bv = bias[gn];
                #pragma unroll
                for (int m = 0; m < 8; ++m) {
                    const int gm0 = row0 + moff + m * 16 + rj;  // token, multiple of 4
                    const int b = gm0 >> 13;
                    const int ntok = gm0 & 8191;
                    float v0 = acc[m][n][0] + bv, v1 = acc[m][n][1] + bv;
                    float v2 = acc[m][n][2] + bv, v3 = acc[m][n][3] + bv;
                    if (do_relu) {
                        v0 = fmaxf(v0, 0.0f); v1 = fmaxf(v1, 0.0f);
                        v2 = fmaxf(v2, 0.0f); v3 = fmaxf(v3, 0.0f);
                    }
                    short4 pk;
                    pk.x = f2bf(v0); pk.y = f2bf(v1); pk.z = f2bf(v2); pk.w = f2bf(v3);
                    *(short4*)(dst + ((size_t)(b * 1024 + hd)) * 8192 + ntok) = pk;
                }
            }
        }
    }
#undef TILE
#undef MF16
#undef RDB
#undef RDA
#undef STG
}

// ---- kv partials: one wave computes kv[64][64] over 256 tokens ----
__global__ __launch_bounds__(64) void kv_partial(const short* __restrict__ ktb,
                                                 const short* __restrict__ vtb,
                                                 float* __restrict__ kvp) {
    const int slice = blockIdx.x;  // 0..31
    const int bh = blockIdx.y;     // 0..63
    const int lane = threadIdx.x;
    const int r16 = lane & 15;
    const short* kb = ktb + (size_t)bh * 64 * 8192;
    const short* vb = vtb + (size_t)bh * 64 * 8192;
    const int n0 = slice << 8;
    f32x4 acc[4][4] = {};
    for (int s = 0; s < 8; ++s) {
        const int nk = n0 + (s << 5) + ((lane >> 4) << 3);
        s16x8 af[4], bf[4];
        #pragma unroll
        for (int m = 0; m < 4; ++m) af[m] = *(const s16x8*)(kb + (size_t)(m * 16 + r16) * 8192 + nk);
        #pragma unroll
        for (int n = 0; n < 4; ++n) bf[n] = *(const s16x8*)(vb + (size_t)(n * 16 + r16) * 8192 + nk);
        #pragma unroll
        for (int m = 0; m < 4; ++m)
            #pragma unroll
            for (int n = 0; n < 4; ++n)
                acc[m][n] = __builtin_amdgcn_mfma_f32_16x16x32_bf16(af[m], bf[n], acc[m][n], 0, 0, 0);
    }
    float* dst = kvp + ((size_t)slice * 64 + bh) * 4096;
    const int rj = (lane >> 4) << 2;
    #pragma unroll
    for (int m = 0; m < 4; ++m)
        #pragma unroll
        for (int n = 0; n < 4; ++n)
            #pragma unroll
            for (int j = 0; j < 4; ++j)
                dst[(size_t)(m * 16 + rj + j) * 64 + n * 16 + r16] = acc[m][n][j];
}

// ---- reduce 32 kv partials, abs-clamp, store transposed bf16 kv_t[bh][e][d] ----
__global__ void kv_reduce(const float* __restrict__ kvp, short* __restrict__ kvt) {
    const int bh = blockIdx.x;
    for (int i = threadIdx.x; i < 4096; i += 256) {
        float s = 0.0f;
        #pragma unroll 8
        for (int sl = 0; sl < 32; ++sl)
            s += kvp[((size_t)sl * 64 + bh) * 4096 + i];
        float a = fabsf(s);
        float cmag = fminf(fmaxf(a, 0.01f), 100.0f);
        float r = (s > 0.0f) ? cmag : ((s < 0.0f) ? -cmag : 0.0f);
        const int d = i >> 6, e = i & 63;
        kvt[(size_t)bh * 4096 + e * 64 + d] = f2bf(r);
    }
}

// ---- o = q @ kv  per (b,h), 256 tokens per block (4 waves x 64) ----
__global__ __launch_bounds__(256) void qkv_out(const short* __restrict__ qb,
                                               const short* __restrict__ kvt,
                                               float* __restrict__ ob) {
    const int bh = blockIdx.y;
    const int b = bh >> 4, h = bh & 15;
    const int tid = threadIdx.x;
    const int wave = tid >> 6, lane = tid & 63;
    const int r16 = lane & 15;
    const size_t mbase = (size_t)b * 8192 + ((size_t)blockIdx.x << 8) + (wave << 6);
    const short* kvb = kvt + (size_t)bh * 4096;
    f32x4 acc[4][4] = {};
    #pragma unroll
    for (int s = 0; s < 2; ++s) {
        const int kq2 = (s << 5) + ((lane >> 4) << 3);
        s16x8 af[4], bf[4];
        #pragma unroll
        for (int m = 0; m < 4; ++m)
            af[m] = *(const s16x8*)(qb + (mbase + m * 16 + r16) * 1024 + h * 64 + kq2);
        #pragma unroll
        for (int n = 0; n < 4; ++n)
            bf[n] = *(const s16x8*)(kvb + (n * 16 + r16) * 64 + kq2);
        #pragma unroll
        for (int m = 0; m < 4; ++m)
            #pragma unroll
            for (int n = 0; n < 4; ++n)
                acc[m][n] = __builtin_amdgcn_mfma_f32_16x16x32_bf16(af[m], bf[n], acc[m][n], 0, 0, 0);
    }
    const int rj = (lane >> 4) << 2;
    #pragma unroll
    for (int m = 0; m < 4; ++m)
        #pragma unroll
        for (int n = 0; n < 4; ++n)
            #pragma unroll
            for (int j = 0; j < 4; ++j)
                ob[(mbase + m * 16 + rj + j) * 1024 + h * 64 + n * 16 + r16] = acc[m][n][j];
}

// ---- LayerNorm over D=1024 + multiply by u, output bf16 ----
__global__ __launch_bounds__(256) void ln_mul(const float* __restrict__ ob,
                                              const short* __restrict__ ub,
                                              const float* __restrict__ lnw,
                                              const float* __restrict__ lnb,
                                              short* __restrict__ yb) {
    const int row = blockIdx.x;
    const int tid = threadIdx.x;
    const float4 v = ((const float4*)(ob + (size_t)row * 1024))[tid];
    float s = v.x + v.y + v.z + v.w;
    float sq = v.x * v.x + v.y * v.y + v.z * v.z + v.w * v.w;
    #pragma unroll
    for (int off = 32; off > 0; off >>= 1) {
        s += __shfl_down(s, off);
        sq += __shfl_down(sq, off);
    }
    __shared__ float ls[4], lq[4];
    const int wave = tid >> 6, lane = tid & 63;
    if (lane == 0) { ls[wave] = s; lq[wave] = sq; }
    __syncthreads();
    const float S = ls[0] + ls[1] + ls[2] + ls[3];
    const float SQ = lq[0] + lq[1] + lq[2] + lq[3];
    const float mu = S * (1.0f / 1024.0f);
    const float var = SQ * (1.0f / 1024.0f) - mu * mu;
    const float rs = rsqrtf(var + 1e-5f);
    const short4 uu = ((const short4*)(ub + (size_t)row * 1024))[tid];
    const float4 w = ((const float4*)lnw)[tid];
    const float4 bb = ((const float4*)lnb)[tid];
    short4 o;
    o.x = f2bf(bf2f(uu.x) * ((v.x - mu) * rs * w.x + bb.x));
    o.y = f2bf(bf2f(uu.y) * ((v.y - mu) * rs * w.y + bb.y));
    o.z = f2bf(bf2f(uu.z) * ((v.z - mu) * rs * w.z + bb.z));
    o.w = f2bf(bf2f(uu.w) * ((v.w - mu) * rs * w.w + bb.w));
    ((short4*)(yb + (size_t)row * 1024))[tid] = o;
}

extern "C" void kernel_launch(void* const* d_in, const int* in_sizes, int n_in,
                              void* d_out, int out_size, void* d_ws, size_t ws_size,
                              hipStream_t stream) {
    (void)in_sizes; (void)n_in; (void)out_size;
    const float* query = (const float*)d_in[0];
    const float* Wq = (const float*)d_in[1];
    const float* bq = (const float*)d_in[2];
    const float* Wk = (const float*)d_in[3];
    const float* bk = (const float*)d_in[4];
    const float* Wv = (const float*)d_in[5];
    const float* bv = (const float*)d_in[6];
    const float* Wu = (const float*)d_in[7];
    const float* bu = (const float*)d_in[8];
    const float* Wo = (const float*)d_in[9];
    const float* bo = (const float*)d_in[10];
    const float* lnw = (const float*)d_in[11];
    const float* lnb = (const float*)d_in[12];
    float* out = (float*)d_out;
    char* ws = (char*)d_ws;
    if (ws_size < 380129280u) return;  // needs ~362.5 MiB

    short* Xb   = (short*)(ws);                    // 64 MiB  (later aliased by yb)
    short* Wcat = (short*)(ws + 67108864);         // 10 MiB
    float* bcat = (float*)(ws + 77594624);         // 20 KiB
    short* qb   = (short*)(ws + 77615104);         // 64 MiB
    short* ktb  = (short*)(ws + 144723968);        // 64 MiB  (later aliased by ob)
    short* vtb  = (short*)(ws + 211832832);        // 64 MiB  (later aliased by ob)
    short* ub   = (short*)(ws + 278941696);        // 64 MiB
    float* kvp  = (float*)(ws + 346050560);        // 32 MiB
    short* kvt  = (short*)(ws + 379604992);        // 512 KiB
    float* ob   = (float*)(ws + 144723968);        // 128 MiB over dead ktb+vtb
    short* yb   = Xb;                              // 64 MiB over dead Xb

    hipFuncSetAttribute(reinterpret_cast<const void*>(&gemm8<0>),
                        hipFuncAttributeMaxDynamicSharedMemorySize, 131072);
    hipFuncSetAttribute(reinterpret_cast<const void*>(&gemm8<1>),
                        hipFuncAttributeMaxDynamicSharedMemorySize, 131072);

    conv_x<<<2048, 256, 0, stream>>>(query, Xb);
    conv_w<<<5120, 256, 0, stream>>>(Wq, Wk, Wv, Wu, Wo, Wcat);
    conv_bias<<<20, 256, 0, stream>>>(bq, bk, bv, bu, bo, bcat);
    gemm8<0><<<2048, 512, 131072, stream>>>(Xb, Wcat, bcat, qb, ktb, vtb, ub, nullptr);
    kv_partial<<<dim3(32, 64), 64, 0, stream>>>(ktb, vtb, kvp);
    kv_reduce<<<64, 256, 0, stream>>>(kvp, kvt);
    qkv_out<<<dim3(32, 64), 256, 0, stream>>>(qb, kvt, ob);
    ln_mul<<<32768, 256, 0, stream>>>(ob, ub, lnw, lnb, yb);
    gemm8<1><<<512, 512, 131072, stream>>>(yb, Wcat + (size_t)4096 * 1024, bcat + 4096,
                                           nullptr, nullptr, nullptr, nullptr, out);
}

// Round 4
// 557.785 us; speedup vs baseline: 1.3538x; 1.0767x over previous
//
#include <hip/hip_runtime.h>

#define M_TOT 32768  // B*N

typedef float f32x4 __attribute__((ext_vector_type(4)));
typedef short s16x8 __attribute__((ext_vector_type(8)));

#define AS1(p) ((__attribute__((address_space(1))) void*)(p))
#define AS3(p) ((__attribute__((address_space(3))) void*)(p))

#define BARRIER() asm volatile("s_barrier" ::: "memory")
#define VMCNT4() asm volatile("s_waitcnt vmcnt(4)" ::: "memory")
#define VMCNT2() asm volatile("s_waitcnt vmcnt(2)" ::: "memory")
#define VMCNT0() asm volatile("s_waitcnt vmcnt(0)" ::: "memory")

__device__ __forceinline__ short f2bf(float f) {
    unsigned u = __builtin_bit_cast(unsigned, f);
    u += 0x7fffu + ((u >> 16) & 1u);
    return (short)(u >> 16);
}
__device__ __forceinline__ float bf2f(short s) {
    unsigned u = ((unsigned)(unsigned short)s) << 16;
    return __builtin_bit_cast(float, u);
}

// ---- convert query f32 -> bf16 ----
__global__ void conv_x(const float* __restrict__ x, short* __restrict__ y) {
    const size_t nchunk = (size_t)M_TOT * 1024 / 8;
    const size_t stride = (size_t)gridDim.x * blockDim.x;
    for (size_t c = (size_t)blockIdx.x * blockDim.x + threadIdx.x; c < nchunk; c += stride) {
        const float4* src = (const float4*)(x + c * 8);
        float4 a = src[0], b = src[1];
        s16x8 r;
        r[0] = f2bf(a.x); r[1] = f2bf(a.y); r[2] = f2bf(a.z); r[3] = f2bf(a.w);
        r[4] = f2bf(b.x); r[5] = f2bf(b.y); r[6] = f2bf(b.z); r[7] = f2bf(b.w);
        *(s16x8*)(y + c * 8) = r;
    }
}

// ---- weights: transpose+convert into Wcat[5120][1024] (rows = out-feature, cols = k) ----
__global__ void conv_w(const float* __restrict__ Wq, const float* __restrict__ Wk,
                       const float* __restrict__ Wv, const float* __restrict__ Wu,
                       const float* __restrict__ Wo, short* __restrict__ Wcat) {
    const int c = blockIdx.x * 256 + threadIdx.x;  // 5120*256 chunks of 4
    const int np = c >> 8;
    const int k0 = (c & 255) << 2;
    const float* W = (np < 1024) ? Wq : (np < 2048) ? Wk : (np < 3072) ? Wv
                   : (np < 4096) ? Wu : Wo;
    const int n = np & 1023;
    short4 r;
    r.x = f2bf(W[(size_t)(k0 + 0) * 1024 + n]);
    r.y = f2bf(W[(size_t)(k0 + 1) * 1024 + n]);
    r.z = f2bf(W[(size_t)(k0 + 2) * 1024 + n]);
    r.w = f2bf(W[(size_t)(k0 + 3) * 1024 + n]);
    *(short4*)(Wcat + (size_t)np * 1024 + k0) = r;
}

__global__ void conv_bias(const float* __restrict__ bq, const float* __restrict__ bk,
                          const float* __restrict__ bv, const float* __restrict__ bu,
                          const float* __restrict__ bo, float* __restrict__ bcat) {
    const int i = blockIdx.x * 256 + threadIdx.x;  // < 5120
    const float* b = (i < 1024) ? bq : (i < 2048) ? bk : (i < 3072) ? bv
                   : (i < 4096) ? bu : bo;
    bcat[i] = b[i & 1023];
}

// ---- 256x256 GEMM, BK=64, 2 LDS buffers, 4 fine phases/K-tile, counted vmcnt ----
// Stage order per tile t (into other buffer, for t+1): (B0,B1)(B2,B3)(A0,A2)(A1,A3).
// Waits: vmcnt(4) end-ph2 (forces A1,A3 of t), vmcnt(2) end-ph4 (forces B*+A0,A2 of t+1).
// LDS rows are 128B (64 bf16); swizzle: 16B-chunk ^= (row&7), pre-swizzled on the
// global source for global_load_lds and applied on ds_read (involution, both sides).
// MFMA cluster is k-outer/n-inner: same-acc RAW distance = 8 MFMA.
template <int MODE>
__global__ __launch_bounds__(512, 2) void gemm8(
        const short* __restrict__ A, const short* __restrict__ W,
        const float* __restrict__ bias,
        short* __restrict__ qb, short* __restrict__ ktb,
        short* __restrict__ vtb, short* __restrict__ ub,
        float* __restrict__ outb) {
    extern __shared__ char lds[];
    const int tid = threadIdx.x;
    const int wave = tid >> 6, lane = tid & 63;
    const int r16 = lane & 15, g = lane >> 4;
    const int moff = (wave >> 2) << 7;  // 0 / 128
    const int noff = (wave & 3) << 6;   // 0 / 64 / 128 / 192

    const int nwg = (MODE == 0) ? 2048 : 512;
    const int NB = (MODE == 0) ? 16 : 4;
    const int bid = blockIdx.x;
    const int swz = (bid & 7) * (nwg >> 3) + (bid >> 3);  // XCD-chunked (nwg%8==0)
    const int mblk = swz / NB, nblk = swz % NB;           // M-outer: XCDs own disjoint A-slices
    const int row0 = mblk << 8, col0 = nblk << 8;

    // ds_read swizzled chunk offsets (lane-constant)
    const int rswz = r16 & 7;
    const int ck0 = (g ^ rswz) << 4;
    const int ck1 = ((4 + g) ^ rswz) << 4;
    const int rowbA = (moff + r16) << 7;
    const int rowbB = (noff + r16) << 7;

    // staging source (lane-constant): row-in-inst = wave*8 + (lane>>3), chunk pre-swizzled
    const char* baseA = (const char*)A + (size_t)(row0 + wave * 8 + (lane >> 3)) * 2048
                        + (((lane & 7) ^ ((lane >> 3) & 7)) << 4);
    const char* baseB = (const char*)W + (size_t)(col0 + wave * 8 + (lane >> 3)) * 2048
                        + (((lane & 7) ^ ((lane >> 3) & 7)) << 4);

#define STG(BASE, J, T, DST)                                                   \
    __builtin_amdgcn_global_load_lds(                                          \
        AS1((BASE) + (size_t)(J) * 131072 + (size_t)(T) * 128),                \
        AS3((DST) + (J) * 8192 + wave * 1024), 16, 0, 0)

#define RDA(V, M, BUFA) {                                                      \
    (V)[0] = *(const s16x8*)((BUFA) + rowbA + (M) * 2048 + ck0);               \
    (V)[1] = *(const s16x8*)((BUFA) + rowbA + (M) * 2048 + ck1); }

#define RDB(V, N, BUFB) {                                                      \
    (V)[0] = *(const s16x8*)((BUFB) + rowbB + (N) * 2048 + ck0);               \
    (V)[1] = *(const s16x8*)((BUFB) + rowbB + (N) * 2048 + ck1); }

#define MF16(P)                                                                \
    _Pragma("unroll") for (int kk = 0; kk < 2; ++kk)                           \
        _Pragma("unroll") for (int n = 0; n < 4; ++n) {                        \
            acc[2*(P)][n]   = __builtin_amdgcn_mfma_f32_16x16x32_bf16(afr[0][kk], bfr[n][kk], acc[2*(P)][n], 0, 0, 0);   \
            acc[2*(P)+1][n] = __builtin_amdgcn_mfma_f32_16x16x32_bf16(afr[1][kk], bfr[n][kk], acc[2*(P)+1][n], 0, 0, 0); \
        }

#define TILE(T, DOSTAGE, TR2, TR4) {                                           \
    char* bA_ = lds + ((T) & 1) * 65536; char* bB_ = bA_ + 32768;              \
    char* sA_ = lds + (((T) + 1) & 1) * 65536; char* sB_ = sA_ + 32768;        \
    s16x8 afr[2][2];                                                           \
    if (DOSTAGE) { STG(baseB, 0, (T) + 1, sB_); STG(baseB, 1, (T) + 1, sB_); } \
    _Pragma("unroll") for (int n = 0; n < 4; ++n) RDB(bfr[n], n, bB_);         \
    RDA(afr[0], 0, bA_); RDA(afr[1], 1, bA_);                                  \
    BARRIER(); __builtin_amdgcn_s_setprio(1); MF16(0);                         \
    __builtin_amdgcn_s_setprio(0); BARRIER();                                  \
    if (DOSTAGE) { STG(baseB, 2, (T) + 1, sB_); STG(baseB, 3, (T) + 1, sB_); } \
    RDA(afr[0], 2, bA_); RDA(afr[1], 3, bA_);                                  \
    BARRIER(); __builtin_amdgcn_s_setprio(1); MF16(1);                         \
    __builtin_amdgcn_s_setprio(0); TR2; BARRIER();                             \
    if (DOSTAGE) { STG(baseA, 0, (T) + 1, sA_); STG(baseA, 2, (T) + 1, sA_); } \
    RDA(afr[0], 4, bA_); RDA(afr[1], 5, bA_);                                  \
    BARRIER(); __builtin_amdgcn_s_setprio(1); MF16(2);                         \
    __builtin_amdgcn_s_setprio(0); BARRIER();                                  \
    if (DOSTAGE) { STG(baseA, 1, (T) + 1, sA_); STG(baseA, 3, (T) + 1, sA_); } \
    RDA(afr[0], 6, bA_); RDA(afr[1], 7, bA_);                                  \
    BARRIER(); __builtin_amdgcn_s_setprio(1); MF16(3);                         \
    __builtin_amdgcn_s_setprio(0); TR4; BARRIER();                             \
}

    f32x4 acc[8][4] = {};
    s16x8 bfr[4][2];

    // prologue: stage tile 0 in steady-state issue order, keep A1,A3 in flight
    STG(baseB, 0, 0, lds + 32768); STG(baseB, 1, 0, lds + 32768);
    STG(baseB, 2, 0, lds + 32768); STG(baseB, 3, 0, lds + 32768);
    STG(baseA, 0, 0, lds);         STG(baseA, 2, 0, lds);
    STG(baseA, 1, 0, lds);         STG(baseA, 3, 0, lds);
    VMCNT2();
    BARRIER();

    #pragma unroll 1
    for (int t = 0; t < 15; ++t) TILE(t, true, VMCNT4(), VMCNT2());
    TILE(15, false, VMCNT0(), (void)0);

    // ---- epilogue ----
    const int rj = (lane >> 4) << 2;
    if (MODE == 1) {
        #pragma unroll
        for (int n = 0; n < 4; ++n) {
            const int gn = col0 + noff + n * 16 + r16;
            const float bv = bias[gn];
            #pragma unroll
            for (int m = 0; m < 8; ++m) {
                const int gm0 = row0 + moff + m * 16 + rj;
                #pragma unroll
                for (int j = 0; j < 4; ++j)
                    outb[(size_t)(gm0 + j) * 1024 + gn] = acc[m][n][j] + bv;
            }
        }
    } else {
        const int seg = col0 >> 10;  // block-uniform (256-col block within one 1024 seg)
        if (seg == 0 || seg == 3) {
            short* dst = (seg == 0) ? qb : ub;
            const bool do_relu = (seg == 0);
            #pragma unroll
            for (int n = 0; n < 4; ++n) {
                const int gn = col0 + noff + n * 16 + r16;
                const int f = gn & 1023;
                const float bv = bias[gn];
                #pragma unroll
                for (int m = 0; m < 8; ++m) {
                    const int gm0 = row0 + moff + m * 16 + rj;
                    #pragma unroll
                    for (int j = 0; j < 4; ++j) {
                        float val = acc[m][n][j] + bv;
                        if (do_relu) val = fmaxf(val, 0.0f);
                        dst[(size_t)(gm0 + j) * 1024 + f] = f2bf(val);
                    }
                }
            }
        } else {
            short* dst = (seg == 1) ? ktb : vtb;
            const bool do_relu = (seg == 1);
            #pragma unroll
            for (int n = 0; n < 4; ++n) {
                const int gn = col0 + noff + n * 16 + r16;
                const int hd = gn & 1023;  // h*64+d
                const float bv = bias[gn];
                #pragma unroll
                for (int m = 0; m < 8; ++m) {
                    const int gm0 = row0 + moff + m * 16 + rj;  // token, multiple of 4
                    const int b = gm0 >> 13;
                    const int ntok = gm0 & 8191;
                    float v0 = acc[m][n][0] + bv, v1 = acc[m][n][1] + bv;
                    float v2 = acc[m][n][2] + bv, v3 = acc[m][n][3] + bv;
                    if (do_relu) {
                        v0 = fmaxf(v0, 0.0f); v1 = fmaxf(v1, 0.0f);
                        v2 = fmaxf(v2, 0.0f); v3 = fmaxf(v3, 0.0f);
                    }
                    short4 pk;
                    pk.x = f2bf(v0); pk.y = f2bf(v1); pk.z = f2bf(v2); pk.w = f2bf(v3);
                    *(short4*)(dst + ((size_t)(b * 1024 + hd)) * 8192 + ntok) = pk;
                }
            }
        }
    }
#undef TILE
#undef MF16
#undef RDB
#undef RDA
#undef STG
}

// ---- kv partials: 4-wave block per (slice, bh); 1024 tokens; LDS cross-wave reduce ----
__global__ __launch_bounds__(256) void kv_partial(const short* __restrict__ ktb,
                                                  const short* __restrict__ vtb,
                                                  float* __restrict__ kvp) {
    __shared__ float red[4][4096];  // 64 KB
    const int slice = blockIdx.x;  // 0..7
    const int bh = blockIdx.y;     // 0..63
    const int wave = threadIdx.x >> 6, lane = threadIdx.x & 63;
    const int r16 = lane & 15;
    const short* kb = ktb + (size_t)bh * 64 * 8192;
    const short* vb = vtb + (size_t)bh * 64 * 8192;
    const int n0 = (slice << 10) + (wave << 8);
    f32x4 acc[4][4] = {};
    for (int s = 0; s < 8; ++s) {
        const int nk = n0 + (s << 5) + ((lane >> 4) << 3);
        s16x8 af[4], bf[4];
        #pragma unroll
        for (int m = 0; m < 4; ++m) af[m] = *(const s16x8*)(kb + (size_t)(m * 16 + r16) * 8192 + nk);
        #pragma unroll
        for (int n = 0; n < 4; ++n) bf[n] = *(const s16x8*)(vb + (size_t)(n * 16 + r16) * 8192 + nk);
        #pragma unroll
        for (int m = 0; m < 4; ++m)
            #pragma unroll
            for (int n = 0; n < 4; ++n)
                acc[m][n] = __builtin_amdgcn_mfma_f32_16x16x32_bf16(af[m], bf[n], acc[m][n], 0, 0, 0);
    }
    const int rj = (lane >> 4) << 2;
    #pragma unroll
    for (int m = 0; m < 4; ++m)
        #pragma unroll
        for (int n = 0; n < 4; ++n)
            #pragma unroll
            for (int j = 0; j < 4; ++j)
                red[wave][(m * 16 + rj + j) * 64 + n * 16 + r16] = acc[m][n][j];
    __syncthreads();
    float* dst = kvp + ((size_t)slice * 64 + bh) * 4096;
    const int i0 = threadIdx.x * 16;
    #pragma unroll
    for (int e = 0; e < 16; e += 4) {
        f32x4 a0 = *(const f32x4*)&red[0][i0 + e];
        f32x4 a1 = *(const f32x4*)&red[1][i0 + e];
        f32x4 a2 = *(const f32x4*)&red[2][i0 + e];
        f32x4 a3 = *(const f32x4*)&red[3][i0 + e];
        *(f32x4*)&dst[i0 + e] = (a0 + a1) + (a2 + a3);
    }
}

// ---- reduce 8 kv partials, abs-clamp, store transposed bf16 kv_t[bh][e][d] ----
__global__ void kv_reduce(const float* __restrict__ kvp, short* __restrict__ kvt) {
    const int bh = blockIdx.x;
    for (int i = threadIdx.x; i < 4096; i += 256) {
        float s = 0.0f;
        #pragma unroll
        for (int sl = 0; sl < 8; ++sl)
            s += kvp[((size_t)sl * 64 + bh) * 4096 + i];
        float a = fabsf(s);
        float cmag = fminf(fmaxf(a, 0.01f), 100.0f);
        float r = (s > 0.0f) ? cmag : ((s < 0.0f) ? -cmag : 0.0f);
        const int d = i >> 6, e = i & 63;
        kvt[(size_t)bh * 4096 + e * 64 + d] = f2bf(r);
    }
}

// ---- fused o = q @ kv -> LayerNorm -> * u -> y (bf16) ----
// 512 blocks x 256 thr; block = 64 tokens; wave = 16 tokens.
// Pass 1: MFMA per head, accumulate row sums/sumsq.  Pass 2: recompute MFMA,
// normalize in-register, bf16 -> wave-private LDS (XOR-swizzled), transposed
// read -> coalesced 16B u-loads and y-stores.
__global__ __launch_bounds__(256) void qkv_ln(const short* __restrict__ qb,
                                              const short* __restrict__ kvt,
                                              const short* __restrict__ ub,
                                              const float* __restrict__ lnw,
                                              const float* __restrict__ lnb,
                                              short* __restrict__ yb) {
    __shared__ short tr[4][1024];  // 2 KB per wave
    const int wave = threadIdx.x >> 6, lane = threadIdx.x & 63;
    const int r16 = lane & 15, g = lane >> 4;
    const size_t rowB = (size_t)blockIdx.x * 64 + wave * 16;
    const int bh0 = (int)((rowB >> 13) << 4);
    const short* qrow = qb + (rowB + r16) * 1024 + g * 8;

    float s[4] = {0, 0, 0, 0}, sq[4] = {0, 0, 0, 0};
    for (int h = 0; h < 16; ++h) {
        const short* kvb = kvt + (size_t)(bh0 + h) * 4096 + g * 8;
        f32x4 a4[4] = {};
        #pragma unroll
        for (int kk = 0; kk < 2; ++kk) {
            const s16x8 af = *(const s16x8*)(qrow + h * 64 + kk * 32);
            #pragma unroll
            for (int n = 0; n < 4; ++n) {
                const s16x8 bf = *(const s16x8*)(kvb + (n * 16 + r16) * 64 + kk * 32);
                a4[n] = __builtin_amdgcn_mfma_f32_16x16x32_bf16(af, bf, a4[n], 0, 0, 0);
            }
        }
        #pragma unroll
        for (int n = 0; n < 4; ++n)
            #pragma unroll
            for (int j = 0; j < 4; ++j) {
                const float v = a4[n][j];
                s[j] += v; sq[j] += v * v;
            }
    }
    #pragma unroll
    for (int j = 0; j < 4; ++j) {
        #pragma unroll
        for (int mk = 1; mk < 16; mk <<= 1) {
            s[j] += __shfl_xor(s[j], mk);
            sq[j] += __shfl_xor(sq[j], mk);
        }
    }
    float mu[4], rs[4];
    #pragma unroll
    for (int j = 0; j < 4; ++j) {
        mu[j] = s[j] * (1.0f / 1024.0f);
        const float var = sq[j] * (1.0f / 1024.0f) - mu[j] * mu[j];
        rs[j] = rsqrtf(var + 1e-5f);
    }

    short* trw = &tr[wave][0];
    const int rdr = lane >> 3;        // 0..7
    const int c0 = (lane & 7) * 8;    // 0..56
    for (int h = 0; h < 16; ++h) {
        const short* kvb = kvt + (size_t)(bh0 + h) * 4096 + g * 8;
        f32x4 a4[4] = {};
        #pragma unroll
        for (int kk = 0; kk < 2; ++kk) {
            const s16x8 af = *(const s16x8*)(qrow + h * 64 + kk * 32);
            #pragma unroll
            for (int n = 0; n < 4; ++n) {
                const s16x8 bf = *(const s16x8*)(kvb + (n * 16 + r16) * 64 + kk * 32);
                a4[n] = __builtin_amdgcn_mfma_f32_16x16x32_bf16(af, bf, a4[n], 0, 0, 0);
            }
        }
        #pragma unroll
        for (int n = 0; n < 4; ++n) {
            const float lw = lnw[h * 64 + n * 16 + r16];
            const float lb = lnb[h * 64 + n * 16 + r16];
            #pragma unroll
            for (int j = 0; j < 4; ++j) {
                const float val = (a4[n][j] - mu[j]) * rs[j] * lw + lb;
                trw[(g * 4 + j) * 64 + ((n ^ g) * 16 + r16)] = f2bf(val);
            }
        }
        #pragma unroll
        for (int p = 0; p < 2; ++p) {
            const int r = rdr + p * 8;
            const s16x8 t = *(const s16x8*)&trw[r * 64 + (((c0 >> 4) ^ (r >> 2)) * 16) + (c0 & 15)];
            const s16x8 uu = *(const s16x8*)(ub + (rowB + r) * 1024 + h * 64 + c0);
            s16x8 o;
            #pragma unroll
            for (int e = 0; e < 8; ++e)
                o[e] = f2bf(bf2f(t[e]) * bf2f(uu[e]));
            *(s16x8*)(yb + (rowB + r) * 1024 + h * 64 + c0) = o;
        }
    }
}

extern "C" void kernel_launch(void* const* d_in, const int* in_sizes, int n_in,
                              void* d_out, int out_size, void* d_ws, size_t ws_size,
                              hipStream_t stream) {
    (void)in_sizes; (void)n_in; (void)out_size;
    const float* query = (const float*)d_in[0];
    const float* Wq = (const float*)d_in[1];
    const float* bq = (const float*)d_in[2];
    const float* Wk = (const float*)d_in[3];
    const float* bk = (const float*)d_in[4];
    const float* Wv = (const float*)d_in[5];
    const float* bv = (const float*)d_in[6];
    const float* Wu = (const float*)d_in[7];
    const float* bu = (const float*)d_in[8];
    const float* Wo = (const float*)d_in[9];
    const float* bo = (const float*)d_in[10];
    const float* lnw = (const float*)d_in[11];
    const float* lnb = (const float*)d_in[12];
    float* out = (float*)d_out;
    char* ws = (char*)d_ws;
    if (ws_size < 380129280u) return;  // uses < 362.5 MiB

    short* Xb   = (short*)(ws);                    // 64 MiB  (later aliased by yb)
    short* Wcat = (short*)(ws + 67108864);         // 10 MiB
    float* bcat = (float*)(ws + 77594624);         // 20 KiB
    short* qb   = (short*)(ws + 77615104);         // 64 MiB
    short* ktb  = (short*)(ws + 144723968);        // 64 MiB
    short* vtb  = (short*)(ws + 211832832);        // 64 MiB
    short* ub   = (short*)(ws + 278941696);        // 64 MiB
    float* kvp  = (float*)(ws + 346050560);        // 8 MiB
    short* kvt  = (short*)(ws + 379604992);        // 512 KiB
    short* yb   = Xb;                              // 64 MiB over dead Xb

    hipFuncSetAttribute(reinterpret_cast<const void*>(&gemm8<0>),
                        hipFuncAttributeMaxDynamicSharedMemorySize, 131072);
    hipFuncSetAttribute(reinterpret_cast<const void*>(&gemm8<1>),
                        hipFuncAttributeMaxDynamicSharedMemorySize, 131072);

    conv_x<<<2048, 256, 0, stream>>>(query, Xb);
    conv_w<<<5120, 256, 0, stream>>>(Wq, Wk, Wv, Wu, Wo, Wcat);
    conv_bias<<<20, 256, 0, stream>>>(bq, bk, bv, bu, bo, bcat);
    gemm8<0><<<2048, 512, 131072, stream>>>(Xb, Wcat, bcat, qb, ktb, vtb, ub, nullptr);
    kv_partial<<<dim3(8, 64), 256, 0, stream>>>(ktb, vtb, kvp);
    kv_reduce<<<64, 256, 0, stream>>>(kvp, kvt);
    qkv_ln<<<512, 256, 0, stream>>>(qb, kvt, ub, lnw, lnb, yb);
    gemm8<1><<<512, 512, 131072, stream>>>(yb, Wcat + (size_t)4096 * 1024, bcat + 4096,
                                           nullptr, nullptr, nullptr, nullptr, out);
}

// Round 5
// 537.438 us; speedup vs baseline: 1.4050x; 1.0379x over previous
//
#include <hip/hip_runtime.h>

#define M_TOT 32768  // B*N

typedef float f32x4 __attribute__((ext_vector_type(4)));
typedef short s16x8 __attribute__((ext_vector_type(8)));

#define AS1(p) ((__attribute__((address_space(1))) void*)(p))
#define AS3(p) ((__attribute__((address_space(3))) void*)(p))

#define BARRIER() asm volatile("s_barrier" ::: "memory")
#define VMCNT4() asm volatile("s_waitcnt vmcnt(4)" ::: "memory")
#define VMCNT2() asm volatile("s_waitcnt vmcnt(2)" ::: "memory")
#define VMCNT0() asm volatile("s_waitcnt vmcnt(0)" ::: "memory")

__device__ __forceinline__ short f2bf(float f) {
    unsigned u = __builtin_bit_cast(unsigned, f);
    u += 0x7fffu + ((u >> 16) & 1u);
    return (short)(u >> 16);
}
__device__ __forceinline__ float bf2f(short s) {
    unsigned u = ((unsigned)(unsigned short)s) << 16;
    return __builtin_bit_cast(float, u);
}

// ---- convert query f32 -> bf16 ----
__global__ void conv_x(const float* __restrict__ x, short* __restrict__ y) {
    const size_t nchunk = (size_t)M_TOT * 1024 / 8;
    const size_t stride = (size_t)gridDim.x * blockDim.x;
    for (size_t c = (size_t)blockIdx.x * blockDim.x + threadIdx.x; c < nchunk; c += stride) {
        const float4* src = (const float4*)(x + c * 8);
        float4 a = src[0], b = src[1];
        s16x8 r;
        r[0] = f2bf(a.x); r[1] = f2bf(a.y); r[2] = f2bf(a.z); r[3] = f2bf(a.w);
        r[4] = f2bf(b.x); r[5] = f2bf(b.y); r[6] = f2bf(b.z); r[7] = f2bf(b.w);
        *(s16x8*)(y + c * 8) = r;
    }
}

// ---- weights: coalesced LDS transpose -> Wcat[5120][1024] (rows = out-feature) ----
__global__ __launch_bounds__(256) void conv_w(const float* __restrict__ Wq,
                                              const float* __restrict__ Wk,
                                              const float* __restrict__ Wv,
                                              const float* __restrict__ Wu,
                                              const float* __restrict__ Wo,
                                              short* __restrict__ Wcat) {
    __shared__ float t[64][65];
    const int b = blockIdx.x;            // 0..1279
    const int mat = b >> 8;              // 0..4
    const int kt = (b >> 4) & 15, nt = b & 15;
    const int k0 = kt << 6, n0 = nt << 6;
    const float* W = (mat == 0) ? Wq : (mat == 1) ? Wk : (mat == 2) ? Wv
                   : (mat == 3) ? Wu : Wo;
    const int rr = threadIdx.x >> 4;     // 0..15
    const int cc = threadIdx.x & 15;     // 0..15
    #pragma unroll
    for (int p = 0; p < 4; ++p) {
        const int row = p * 16 + rr;
        const float4 v = *(const float4*)(W + (size_t)(k0 + row) * 1024 + n0 + cc * 4);
        t[row][cc * 4 + 0] = v.x; t[row][cc * 4 + 1] = v.y;
        t[row][cc * 4 + 2] = v.z; t[row][cc * 4 + 3] = v.w;
    }
    __syncthreads();
    #pragma unroll
    for (int p = 0; p < 4; ++p) {
        const int nr = p * 16 + rr;
        short4 r;
        r.x = f2bf(t[cc * 4 + 0][nr]); r.y = f2bf(t[cc * 4 + 1][nr]);
        r.z = f2bf(t[cc * 4 + 2][nr]); r.w = f2bf(t[cc * 4 + 3][nr]);
        *(short4*)(Wcat + (size_t)(mat * 1024 + n0 + nr) * 1024 + k0 + cc * 4) = r;
    }
}

__global__ void conv_bias(const float* __restrict__ bq, const float* __restrict__ bk,
                          const float* __restrict__ bv, const float* __restrict__ bu,
                          const float* __restrict__ bo, float* __restrict__ bcat) {
    const int i = blockIdx.x * 256 + threadIdx.x;  // < 5120
    const float* b = (i < 1024) ? bq : (i < 2048) ? bk : (i < 3072) ? bv
                   : (i < 4096) ? bu : bo;
    bcat[i] = b[i & 1023];
}

// ---- 256x256 GEMM, BK=64, 2 LDS buffers, 2 free-running windows/K-tile ----
// Stage ledger per tile t (staging t+1): W1 issues B0..B3, W2 issues A0,A2,A1,A3.
// VMCNT4+barrier mid-tile forces A1,A3(t) visible before m=4..7 reads;
// VMCNT2+barrier at tile end forces B*,A0,A2(t+1) visible for next W1.
// Only 2 barriers/K-tile: ds_read streaming overlaps MFMA issue within windows.
// LDS rows 128B; swizzle: 16B-chunk ^= (row&7) on both global source and ds_read.
template <int MODE>
__global__ __launch_bounds__(512, 2) void gemm8(
        const short* __restrict__ A, const short* __restrict__ W,
        const float* __restrict__ bias,
        short* __restrict__ qb, short* __restrict__ ktb,
        short* __restrict__ vtb, short* __restrict__ ub,
        float* __restrict__ outb) {
    extern __shared__ char lds[];
    const int tid = threadIdx.x;
    const int wave = tid >> 6, lane = tid & 63;
    const int r16 = lane & 15, g = lane >> 4;
    const int moff = (wave >> 2) << 7;  // 0 / 128
    const int noff = (wave & 3) << 6;   // 0 / 64 / 128 / 192

    const int nwg = (MODE == 0) ? 2048 : 512;
    const int NB = (MODE == 0) ? 16 : 4;
    const int bid = blockIdx.x;
    const int swz = (bid & 7) * (nwg >> 3) + (bid >> 3);  // XCD-chunked (nwg%8==0)
    const int mblk = swz / NB, nblk = swz % NB;           // M-outer: XCDs own disjoint A-slices
    const int row0 = mblk << 8, col0 = nblk << 8;

    // ds_read swizzled chunk offsets (lane-constant)
    const int rswz = r16 & 7;
    const int ck0 = (g ^ rswz) << 4;
    const int ck1 = ((4 + g) ^ rswz) << 4;
    const int rowbA = (moff + r16) << 7;
    const int rowbB = (noff + r16) << 7;

    // staging source (lane-constant): row-in-inst = wave*8 + (lane>>3), chunk pre-swizzled
    const char* baseA = (const char*)A + (size_t)(row0 + wave * 8 + (lane >> 3)) * 2048
                        + (((lane & 7) ^ ((lane >> 3) & 7)) << 4);
    const char* baseB = (const char*)W + (size_t)(col0 + wave * 8 + (lane >> 3)) * 2048
                        + (((lane & 7) ^ ((lane >> 3) & 7)) << 4);

#define STG(BASE, J, T, DST)                                                   \
    __builtin_amdgcn_global_load_lds(                                          \
        AS1((BASE) + (size_t)(J) * 131072 + (size_t)(T) * 128),                \
        AS3((DST) + (J) * 8192 + wave * 1024), 16, 0, 0)

#define RDA(V, M, BUFA) {                                                      \
    (V)[0] = *(const s16x8*)((BUFA) + rowbA + (M) * 2048 + ck0);               \
    (V)[1] = *(const s16x8*)((BUFA) + rowbA + (M) * 2048 + ck1); }

#define RDB(V, N, BUFB) {                                                      \
    (V)[0] = *(const s16x8*)((BUFB) + rowbB + (N) * 2048 + ck0);               \
    (V)[1] = *(const s16x8*)((BUFB) + rowbB + (N) * 2048 + ck1); }

#define MF16(P, A0, A1)                                                        \
    _Pragma("unroll") for (int kk = 0; kk < 2; ++kk)                           \
        _Pragma("unroll") for (int n = 0; n < 4; ++n) {                        \
            acc[2*(P)][n]   = __builtin_amdgcn_mfma_f32_16x16x32_bf16((A0)[kk], bfr[n][kk], acc[2*(P)][n], 0, 0, 0);   \
            acc[2*(P)+1][n] = __builtin_amdgcn_mfma_f32_16x16x32_bf16((A1)[kk], bfr[n][kk], acc[2*(P)+1][n], 0, 0, 0); \
        }

#define TILE(T, DOSTAGE, TRmid, TRend) {                                       \
    char* bA_ = lds + ((T) & 1) * 65536; char* bB_ = bA_ + 32768;              \
    char* sA_ = lds + (((T) + 1) & 1) * 65536; char* sB_ = sA_ + 32768;        \
    s16x8 a0[2], a1[2], a2[2], a3[2];                                          \
    if (DOSTAGE) { STG(baseB, 0, (T) + 1, sB_); STG(baseB, 1, (T) + 1, sB_);   \
                   STG(baseB, 2, (T) + 1, sB_); STG(baseB, 3, (T) + 1, sB_); } \
    _Pragma("unroll") for (int n = 0; n < 4; ++n) RDB(bfr[n], n, bB_);         \
    RDA(a0, 0, bA_); RDA(a1, 1, bA_); RDA(a2, 2, bA_); RDA(a3, 3, bA_);        \
    __builtin_amdgcn_s_setprio(1);                                             \
    MF16(0, a0, a1); MF16(1, a2, a3);                                          \
    __builtin_amdgcn_s_setprio(0);                                             \
    TRmid; BARRIER();                                                          \
    if (DOSTAGE) { STG(baseA, 0, (T) + 1, sA_); STG(baseA, 2, (T) + 1, sA_);   \
                   STG(baseA, 1, (T) + 1, sA_); STG(baseA, 3, (T) + 1, sA_); } \
    RDA(a0, 4, bA_); RDA(a1, 5, bA_); RDA(a2, 6, bA_); RDA(a3, 7, bA_);        \
    __builtin_amdgcn_s_setprio(1);                                             \
    MF16(2, a0, a1); MF16(3, a2, a3);                                          \
    __builtin_amdgcn_s_setprio(0);                                             \
    TRend; BARRIER(); }

    f32x4 acc[8][4] = {};
    s16x8 bfr[4][2];

    // prologue: stage tile 0 in steady-state issue order, keep A1,A3 in flight
    STG(baseB, 0, 0, lds + 32768); STG(baseB, 1, 0, lds + 32768);
    STG(baseB, 2, 0, lds + 32768); STG(baseB, 3, 0, lds + 32768);
    STG(baseA, 0, 0, lds);         STG(baseA, 2, 0, lds);
    STG(baseA, 1, 0, lds);         STG(baseA, 3, 0, lds);
    VMCNT2();
    BARRIER();

    #pragma unroll 1
    for (int t = 0; t < 15; ++t) TILE(t, true, VMCNT4(), VMCNT2());
    TILE(15, false, VMCNT0(), (void)0);

    // ---- epilogue ----
    const int rj = (lane >> 4) << 2;
    if (MODE == 1) {
        #pragma unroll
        for (int n = 0; n < 4; ++n) {
            const int gn = col0 + noff + n * 16 + r16;
            const float bv = bias[gn];
            #pragma unroll
            for (int m = 0; m < 8; ++m) {
                const int gm0 = row0 + moff + m * 16 + rj;
                #pragma unroll
                for (int j = 0; j < 4; ++j)
                    outb[(size_t)(gm0 + j) * 1024 + gn] = acc[m][n][j] + bv;
            }
        }
    } else {
        const int seg = col0 >> 10;  // block-uniform (256-col block within one 1024 seg)
        if (seg == 0 || seg == 3) {
            short* dst = (seg == 0) ? qb : ub;
            const bool do_relu = (seg == 0);
            #pragma unroll
            for (int n = 0; n < 4; ++n) {
                const int gn = col0 + noff + n * 16 + r16;
                const int f = gn & 1023;
                const float bv = bias[gn];
                #pragma unroll
                for (int m = 0; m < 8; ++m) {
                    const int gm0 = row0 + moff + m * 16 + rj;
                    #pragma unroll
                    for (int j = 0; j < 4; ++j) {
                        float val = acc[m][n][j] + bv;
                        if (do_relu) val = fmaxf(val, 0.0f);
                        dst[(size_t)(gm0 + j) * 1024 + f] = f2bf(val);
                    }
                }
            }
        } else {
            short* dst = (seg == 1) ? ktb : vtb;
            const bool do_relu = (seg == 1);
            #pragma unroll
            for (int n = 0; n < 4; ++n) {
                const int gn = col0 + noff + n * 16 + r16;
                const int hd = gn & 1023;  // h*64+d
                const float bv = bias[gn];
                #pragma unroll
                for (int m = 0; m < 8; ++m) {
                    const int gm0 = row0 + moff + m * 16 + rj;  // token, multiple of 4
                    const int b = gm0 >> 13;
                    const int ntok = gm0 & 8191;
                    float v0 = acc[m][n][0] + bv, v1 = acc[m][n][1] + bv;
                    float v2 = acc[m][n][2] + bv, v3 = acc[m][n][3] + bv;
                    if (do_relu) {
                        v0 = fmaxf(v0, 0.0f); v1 = fmaxf(v1, 0.0f);
                        v2 = fmaxf(v2, 0.0f); v3 = fmaxf(v3, 0.0f);
                    }
                    short4 pk;
                    pk.x = f2bf(v0); pk.y = f2bf(v1); pk.z = f2bf(v2); pk.w = f2bf(v3);
                    *(short4*)(dst + ((size_t)(b * 1024 + hd)) * 8192 + ntok) = pk;
                }
            }
        }
    }
#undef TILE
#undef MF16
#undef RDB
#undef RDA
#undef STG
}

// ---- kv partials: 4-wave block per (slice, bh); 1024 tokens; LDS cross-wave reduce ----
__global__ __launch_bounds__(256) void kv_partial(const short* __restrict__ ktb,
                                                  const short* __restrict__ vtb,
                                                  float* __restrict__ kvp) {
    __shared__ float red[4][4096];  // 64 KB
    const int slice = blockIdx.x;  // 0..7
    const int bh = blockIdx.y;     // 0..63
    const int wave = threadIdx.x >> 6, lane = threadIdx.x & 63;
    const int r16 = lane & 15;
    const short* kb = ktb + (size_t)bh * 64 * 8192;
    const short* vb = vtb + (size_t)bh * 64 * 8192;
    const int n0 = (slice << 10) + (wave << 8);
    f32x4 acc[4][4] = {};
    for (int s = 0; s < 8; ++s) {
        const int nk = n0 + (s << 5) + ((lane >> 4) << 3);
        s16x8 af[4], bf[4];
        #pragma unroll
        for (int m = 0; m < 4; ++m) af[m] = *(const s16x8*)(kb + (size_t)(m * 16 + r16) * 8192 + nk);
        #pragma unroll
        for (int n = 0; n < 4; ++n) bf[n] = *(const s16x8*)(vb + (size_t)(n * 16 + r16) * 8192 + nk);
        #pragma unroll
        for (int m = 0; m < 4; ++m)
            #pragma unroll
            for (int n = 0; n < 4; ++n)
                acc[m][n] = __builtin_amdgcn_mfma_f32_16x16x32_bf16(af[m], bf[n], acc[m][n], 0, 0, 0);
    }
    const int rj = (lane >> 4) << 2;
    #pragma unroll
    for (int m = 0; m < 4; ++m)
        #pragma unroll
        for (int n = 0; n < 4; ++n)
            #pragma unroll
            for (int j = 0; j < 4; ++j)
                red[wave][(m * 16 + rj + j) * 64 + n * 16 + r16] = acc[m][n][j];
    __syncthreads();
    float* dst = kvp + ((size_t)slice * 64 + bh) * 4096;
    const int i0 = threadIdx.x * 16;
    #pragma unroll
    for (int e = 0; e < 16; e += 4) {
        f32x4 a0 = *(const f32x4*)&red[0][i0 + e];
        f32x4 a1 = *(const f32x4*)&red[1][i0 + e];
        f32x4 a2 = *(const f32x4*)&red[2][i0 + e];
        f32x4 a3 = *(const f32x4*)&red[3][i0 + e];
        *(f32x4*)&dst[i0 + e] = (a0 + a1) + (a2 + a3);
    }
}

// ---- reduce 8 kv partials, abs-clamp, store transposed bf16 kv_t[bh][e][d] ----
__global__ void kv_reduce(const float* __restrict__ kvp, short* __restrict__ kvt) {
    const int bh = blockIdx.x;
    for (int i = threadIdx.x; i < 4096; i += 256) {
        float s = 0.0f;
        #pragma unroll
        for (int sl = 0; sl < 8; ++sl)
            s += kvp[((size_t)sl * 64 + bh) * 4096 + i];
        float a = fabsf(s);
        float cmag = fminf(fmaxf(a, 0.01f), 100.0f);
        float r = (s > 0.0f) ? cmag : ((s < 0.0f) ? -cmag : 0.0f);
        const int d = i >> 6, e = i & 63;
        kvt[(size_t)bh * 4096 + e * 64 + d] = f2bf(r);
    }
}

// ---- fused o = q @ kv -> LayerNorm -> * u -> y (bf16) ----
__global__ __launch_bounds__(256) void qkv_ln(const short* __restrict__ qb,
                                              const short* __restrict__ kvt,
                                              const short* __restrict__ ub,
                                              const float* __restrict__ lnw,
                                              const float* __restrict__ lnb,
                                              short* __restrict__ yb) {
    __shared__ short tr[4][1024];  // 2 KB per wave
    const int wave = threadIdx.x >> 6, lane = threadIdx.x & 63;
    const int r16 = lane & 15, g = lane >> 4;
    const size_t rowB = (size_t)blockIdx.x * 64 + wave * 16;
    const int bh0 = (int)((rowB >> 13) << 4);
    const short* qrow = qb + (rowB + r16) * 1024 + g * 8;

    float s[4] = {0, 0, 0, 0}, sq[4] = {0, 0, 0, 0};
    for (int h = 0; h < 16; ++h) {
        const short* kvb = kvt + (size_t)(bh0 + h) * 4096 + g * 8;
        f32x4 a4[4] = {};
        #pragma unroll
        for (int kk = 0; kk < 2; ++kk) {
            const s16x8 af = *(const s16x8*)(qrow + h * 64 + kk * 32);
            #pragma unroll
            for (int n = 0; n < 4; ++n) {
                const s16x8 bf = *(const s16x8*)(kvb + (n * 16 + r16) * 64 + kk * 32);
                a4[n] = __builtin_amdgcn_mfma_f32_16x16x32_bf16(af, bf, a4[n], 0, 0, 0);
            }
        }
        #pragma unroll
        for (int n = 0; n < 4; ++n)
            #pragma unroll
            for (int j = 0; j < 4; ++j) {
                const float v = a4[n][j];
                s[j] += v; sq[j] += v * v;
            }
    }
    #pragma unroll
    for (int j = 0; j < 4; ++j) {
        #pragma unroll
        for (int mk = 1; mk < 16; mk <<= 1) {
            s[j] += __shfl_xor(s[j], mk);
            sq[j] += __shfl_xor(sq[j], mk);
        }
    }
    float mu[4], rs[4];
    #pragma unroll
    for (int j = 0; j < 4; ++j) {
        mu[j] = s[j] * (1.0f / 1024.0f);
        const float var = sq[j] * (1.0f / 1024.0f) - mu[j] * mu[j];
        rs[j] = rsqrtf(var + 1e-5f);
    }

    short* trw = &tr[wave][0];
    const int rdr = lane >> 3;        // 0..7
    const int c0 = (lane & 7) * 8;    // 0..56
    for (int h = 0; h < 16; ++h) {
        const short* kvb = kvt + (size_t)(bh0 + h) * 4096 + g * 8;
        f32x4 a4[4] = {};
        #pragma unroll
        for (int kk = 0; kk < 2; ++kk) {
            const s16x8 af = *(const s16x8*)(qrow + h * 64 + kk * 32);
            #pragma unroll
            for (int n = 0; n < 4; ++n) {
                const s16x8 bf = *(const s16x8*)(kvb + (n * 16 + r16) * 64 + kk * 32);
                a4[n] = __builtin_amdgcn_mfma_f32_16x16x32_bf16(af, bf, a4[n], 0, 0, 0);
            }
        }
        #pragma unroll
        for (int n = 0; n < 4; ++n) {
            const float lw = lnw[h * 64 + n * 16 + r16];
            const float lb = lnb[h * 64 + n * 16 + r16];
            #pragma unroll
            for (int j = 0; j < 4; ++j) {
                const float val = (a4[n][j] - mu[j]) * rs[j] * lw + lb;
                trw[(g * 4 + j) * 64 + ((n ^ g) * 16 + r16)] = f2bf(val);
            }
        }
        #pragma unroll
        for (int p = 0; p < 2; ++p) {
            const int r = rdr + p * 8;
            const s16x8 t = *(const s16x8*)&trw[r * 64 + (((c0 >> 4) ^ (r >> 2)) * 16) + (c0 & 15)];
            const s16x8 uu = *(const s16x8*)(ub + (rowB + r) * 1024 + h * 64 + c0);
            s16x8 o;
            #pragma unroll
            for (int e = 0; e < 8; ++e)
                o[e] = f2bf(bf2f(t[e]) * bf2f(uu[e]));
            *(s16x8*)(yb + (rowB + r) * 1024 + h * 64 + c0) = o;
        }
    }
}

extern "C" void kernel_launch(void* const* d_in, const int* in_sizes, int n_in,
                              void* d_out, int out_size, void* d_ws, size_t ws_size,
                              hipStream_t stream) {
    (void)in_sizes; (void)n_in; (void)out_size;
    const float* query = (const float*)d_in[0];
    const float* Wq = (const float*)d_in[1];
    const float* bq = (const float*)d_in[2];
    const float* Wk = (const float*)d_in[3];
    const float* bk = (const float*)d_in[4];
    const float* Wv = (const float*)d_in[5];
    const float* bv = (const float*)d_in[6];
    const float* Wu = (const float*)d_in[7];
    const float* bu = (const float*)d_in[8];
    const float* Wo = (const float*)d_in[9];
    const float* bo = (const float*)d_in[10];
    const float* lnw = (const float*)d_in[11];
    const float* lnb = (const float*)d_in[12];
    float* out = (float*)d_out;
    char* ws = (char*)d_ws;
    if (ws_size < 380129280u) return;  // uses < 362.5 MiB

    short* Xb   = (short*)(ws);                    // 64 MiB  (later aliased by yb)
    short* Wcat = (short*)(ws + 67108864);         // 10 MiB
    float* bcat = (float*)(ws + 77594624);         // 20 KiB
    short* qb   = (short*)(ws + 77615104);         // 64 MiB
    short* ktb  = (short*)(ws + 144723968);        // 64 MiB
    short* vtb  = (short*)(ws + 211832832);        // 64 MiB
    short* ub   = (short*)(ws + 278941696);        // 64 MiB
    float* kvp  = (float*)(ws + 346050560);        // 8 MiB
    short* kvt  = (short*)(ws + 379604992);        // 512 KiB
    short* yb   = Xb;                              // 64 MiB over dead Xb

    hipFuncSetAttribute(reinterpret_cast<const void*>(&gemm8<0>),
                        hipFuncAttributeMaxDynamicSharedMemorySize, 131072);
    hipFuncSetAttribute(reinterpret_cast<const void*>(&gemm8<1>),
                        hipFuncAttributeMaxDynamicSharedMemorySize, 131072);

    conv_x<<<2048, 256, 0, stream>>>(query, Xb);
    conv_w<<<1280, 256, 0, stream>>>(Wq, Wk, Wv, Wu, Wo, Wcat);
    conv_bias<<<20, 256, 0, stream>>>(bq, bk, bv, bu, bo, bcat);
    gemm8<0><<<2048, 512, 131072, stream>>>(Xb, Wcat, bcat, qb, ktb, vtb, ub, nullptr);
    kv_partial<<<dim3(8, 64), 256, 0, stream>>>(ktb, vtb, kvp);
    kv_reduce<<<64, 256, 0, stream>>>(kvp, kvt);
    qkv_ln<<<512, 256, 0, stream>>>(qb, kvt, ub, lnw, lnb, yb);
    gemm8<1><<<512, 512, 131072, stream>>>(yb, Wcat + (size_t)4096 * 1024, bcat + 4096,
                                           nullptr, nullptr, nullptr, nullptr, out);
}